// Round 10
// baseline (2787.870 us; speedup 1.0000x reference)
//
#include <hip/hip_runtime.h>
#include <hip/hip_fp16.h>
#include <cstdint>
#include <cstddef>

#define NN 100000
#define EE 400000
#define CC 16
#define LL 16
#define NB 32      // stats atomic buckets
#define NPB 32     // nodes per block in layer kernels (100000 = 3125*32)

typedef unsigned int uint;

// ---------- device helpers ----------
__device__ __forceinline__ float lrelu(float v){ return v > 0.0f ? v : 0.01f*v; }

__device__ __forceinline__ float waveSum(float v){
#pragma unroll
  for (int off = 32; off >= 1; off >>= 1) v += __shfl_xor(v, off);
  return v;
}

__device__ __forceinline__ float fma4(float4 w, float4 v, float a){
  a = fmaf(w.x, v.x, a); a = fmaf(w.y, v.y, a);
  a = fmaf(w.z, v.z, a); a = fmaf(w.w, v.w, a);
  return a;
}

__device__ __forceinline__ uint pack_h2(float a, float b){
  __half2 h = __floats2half2_rn(a, b);
  return *reinterpret_cast<uint*>(&h);
}
__device__ __forceinline__ float2 unpack_h2(uint v){
  __half2 h = *reinterpret_cast<__half2*>(&v);
  return __half22float2(h);
}

// ---------- init: count degrees (int atomics only) ----------
__global__ __launch_bounds__(256) void k_count(const int* __restrict__ ei,
    int* __restrict__ cdst, int* __restrict__ call)
{
  int t = blockIdx.x*256 + threadIdx.x;
  if (t >= EE) return;
  int s = ei[t], d = ei[EE + t];
  atomicAdd(&cdst[d], 1);
  atomicAdd(&call[s], 1);
  atomicAdd(&call[d], 1);
}

// ---------- dual exclusive scan (SEG=1024/block) ----------
__device__ __forceinline__ void scan_one(const int* __restrict__ cnt,
    int* __restrict__ rp, int* __restrict__ bsums, int n, int* sd)
{
  int tid = threadIdx.x;
  int base = blockIdx.x*1024 + tid*4;
  int v0=0,v1=0,v2=0,v3=0;
  if (base+0 < n) v0 = cnt[base+0];
  if (base+1 < n) v1 = cnt[base+1];
  if (base+2 < n) v2 = cnt[base+2];
  if (base+3 < n) v3 = cnt[base+3];
  int tot = v0+v1+v2+v3;
  sd[tid] = tot; __syncthreads();
  for (int off=1; off<256; off<<=1){
    int add = (tid>=off) ? sd[tid-off] : 0;
    __syncthreads();
    sd[tid] += add;
    __syncthreads();
  }
  int excl = sd[tid] - tot;
  if (base+0 < n) rp[base+0] = excl;
  if (base+1 < n) rp[base+1] = excl+v0;
  if (base+2 < n) rp[base+2] = excl+v0+v1;
  if (base+3 < n) rp[base+3] = excl+v0+v1+v2;
  if (tid==255) bsums[blockIdx.x] = sd[255];
  __syncthreads();
}

__global__ __launch_bounds__(256) void k_scan1(const int* __restrict__ ca,
    int* __restrict__ rpa, int* __restrict__ bsa,
    const int* __restrict__ cb, int* __restrict__ rpb, int* __restrict__ bsb, int n)
{
  __shared__ int sd[256];
  scan_one(ca, rpa, bsa, n, sd);
  scan_one(cb, rpb, bsb, n, sd);
}

__device__ __forceinline__ void scan2_one(const int* __restrict__ bsums,
    int* __restrict__ boff, int nseg, int* sd)
{
  int tid = threadIdx.x;
  int v = (tid < nseg) ? bsums[tid] : 0;
  sd[tid] = v; __syncthreads();
  for (int off=1; off<256; off<<=1){
    int add = (tid>=off) ? sd[tid-off] : 0;
    __syncthreads();
    sd[tid] += add;
    __syncthreads();
  }
  if (tid < nseg) boff[tid] = sd[tid] - v;
  __syncthreads();
}

__global__ __launch_bounds__(256) void k_scan2(const int* __restrict__ bsa,
    int* __restrict__ boffa, const int* __restrict__ bsb, int* __restrict__ boffb, int nseg)
{
  __shared__ int sd[256];
  scan2_one(bsa, boffa, nseg, sd);
  scan2_one(bsb, boffb, nseg, sd);
}

__global__ __launch_bounds__(256) void k_scan3(
    int* __restrict__ rpa, int* __restrict__ cura, const int* __restrict__ boffa, int totala,
    int* __restrict__ rpb, int* __restrict__ curb, const int* __restrict__ boffb, int totalb, int n)
{
  int adda = boffa[blockIdx.x];
  int addb = boffb[blockIdx.x];
  int base = blockIdx.x*1024 + threadIdx.x*4;
#pragma unroll
  for (int i=0;i<4;i++){
    if (base+i < n){
      int va = rpa[base+i] + adda; rpa[base+i] = va; cura[base+i] = va;
      int vb = rpb[base+i] + addb; rpb[base+i] = vb; curb[base+i] = vb;
    }
  }
  if (blockIdx.x==0 && threadIdx.x==0){ rpa[n] = totala; rpb[n] = totalb; }
}

// ---------- fill: dst-sorted (src,dst) pairs + all-CSR edge list ----------
__global__ __launch_bounds__(256) void k_fill(const int* __restrict__ ei,
    int* __restrict__ cur, int2* __restrict__ sd,
    int* __restrict__ cur_all, int* __restrict__ list_all)
{
  int t = blockIdx.x*256 + threadIdx.x;
  if (t >= EE) return;
  int s = ei[t], d = ei[EE + t];
  int p = atomicAdd(&cur[d], 1);
  sd[p] = make_int2(s, d);
  int pa = atomicAdd(&cur_all[s], 1);
  list_all[pa] = t;
  int pb = atomicAdd(&cur_all[d], 1);
  list_all[pb] = t;
}

// ---------- x0 = mean of incident edge features; invdeg = 1/clip(deg_in,1) ----------
__global__ __launch_bounds__(256) void k_gather0(const float* __restrict__ ef,
    const int* __restrict__ rp_all, const int* __restrict__ list_all,
    const int* __restrict__ rp, float* __restrict__ x0, float* __restrict__ invdeg)
{
  int t = blockIdx.x*256 + threadIdx.x;
  if (t >= NN*CC) return;
  int n = t >> 4, c = t & 15;
  int beg = rp_all[n], end = rp_all[n+1];
  float acc = 0.0f;
  for (int i=beg; i<end; i++){
    acc += ef[(size_t)list_all[i]*CC + c];
  }
  float dg = fmaxf((float)(end-beg), 1.0f);
  x0[t] = acc / dg;
  if (c == 0){
    int di = rp[n+1] - rp[n];
    invdeg[n] = 1.0f / fmaxf((float)di, 1.0f);
  }
}

// ---------- per-layer: m over node-range edges -> fp16 store + BN stats ----------
// block b owns edges [rp[32b], rp[32b+32]) -- SAME decomposition as k_node,
// so block b of k_node reads exactly what block b wrote (XCD-local L2).
__global__ __launch_bounds__(256) void k_edge(const float* __restrict__ x,
    const int2* __restrict__ sd, const int* __restrict__ rp,
    const float* __restrict__ W, const float* __restrict__ b,
    uint* __restrict__ mh, double* __restrict__ st)
{
  __shared__ float sW[512];
  __shared__ float sb16[16];
  __shared__ float sredS[64], sredQ[64];
  for (int i=threadIdx.x; i<512; i+=256) sW[i] = W[i];
  if (threadIdx.x < 16) sb16[threadIdx.x] = b[threadIdx.x];
  __syncthreads();

  int nlo = blockIdx.x * NPB;
  int elo = rp[nlo], ehi = rp[nlo + NPB];

  float ls[16], lq[16];
#pragma unroll
  for (int c=0;c<16;c++){ ls[c]=0.f; lq[c]=0.f; }

  for (int i = elo + threadIdx.x; i < ehi; i += 256){
    int2 p = sd[i];
    const float4* xd4 = (const float4*)(x + (size_t)p.y*CC);
    const float4* xs4 = (const float4*)(x + (size_t)p.x*CC);
    float4 xd0=xd4[0], xd1=xd4[1], xd2=xd4[2], xd3=xd4[3];
    float4 xs0=xs4[0], xs1=xs4[1], xs2=xs4[2], xs3=xs4[3];
    uint pk[8];
#pragma unroll
    for (int q=0;q<8;q++){
      int c0 = 2*q, c1 = 2*q+1;
      const float4* w0 = (const float4*)(sW + c0*32);
      const float4* w1 = (const float4*)(sW + c1*32);
      float a0 = sb16[c0], a1 = sb16[c1];
      a0 = fma4(w0[0],xd0,a0); a0 = fma4(w0[1],xd1,a0);
      a0 = fma4(w0[2],xd2,a0); a0 = fma4(w0[3],xd3,a0);
      a0 = fma4(w0[4],xs0,a0); a0 = fma4(w0[5],xs1,a0);
      a0 = fma4(w0[6],xs2,a0); a0 = fma4(w0[7],xs3,a0);
      a1 = fma4(w1[0],xd0,a1); a1 = fma4(w1[1],xd1,a1);
      a1 = fma4(w1[2],xd2,a1); a1 = fma4(w1[3],xd3,a1);
      a1 = fma4(w1[4],xs0,a1); a1 = fma4(w1[5],xs1,a1);
      a1 = fma4(w1[6],xs2,a1); a1 = fma4(w1[7],xs3,a1);
      ls[c0] += a0; lq[c0] += a0*a0;
      ls[c1] += a1; lq[c1] += a1*a1;
      pk[q] = pack_h2(a0, a1);
    }
    uint4* po = (uint4*)(mh + (size_t)i*8);
    po[0] = make_uint4(pk[0],pk[1],pk[2],pk[3]);
    po[1] = make_uint4(pk[4],pk[5],pk[6],pk[7]);
  }

  int lane = threadIdx.x & 63, w = threadIdx.x >> 6;
#pragma unroll
  for (int c=0;c<16;c++){
    float rs = waveSum(ls[c]);
    float rq = waveSum(lq[c]);
    if (lane == 0){ sredS[w*16+c] = rs; sredQ[w*16+c] = rq; }
  }
  __syncthreads();
  double* stb = st + (size_t)(blockIdx.x & (NB-1))*32;
  if (threadIdx.x < 16){
    int c = threadIdx.x;
    float tot = sredS[c] + sredS[16+c] + sredS[32+c] + sredS[48+c];
    unsafeAtomicAdd(&stb[c], (double)tot);
  } else if (threadIdx.x < 32){
    int c = threadIdx.x - 16;
    float tot = sredQ[c] + sredQ[16+c] + sredQ[32+c] + sredQ[48+c];
    unsafeAtomicAdd(&stb[16+c], (double)tot);
  }
}

// ---------- per-layer: finalize BN, leaky, contiguous segment-mean by dst ----------
// 8 threads per node, 2 channels per thread; block b owns nodes [32b, 32b+32)
__global__ __launch_bounds__(256) void k_node(const uint* __restrict__ mh,
    const int* __restrict__ rp,
    const float* __restrict__ invdeg, const double* __restrict__ st,
    const float* __restrict__ g, const float* __restrict__ bt,
    float* __restrict__ xout)
{
  __shared__ float sA[16], sB[16];
  if (threadIdx.x < 16){
    int c = threadIdx.x;
    double S = 0.0, Q = 0.0;
#pragma unroll
    for (int k=0;k<NB;k++){ S += st[k*32 + c]; Q += st[k*32 + 16 + c]; }
    double mu  = S * (1.0/EE);
    double var = Q * (1.0/EE) - mu*mu;
    float sc = rsqrtf((float)var + 1e-5f);
    float A = sc * g[c];
    sA[c] = A; sB[c] = bt[c] - (float)mu * A;
  }
  __syncthreads();
  int t = blockIdx.x*256 + threadIdx.x;
  int n = t >> 3, cp = t & 7;
  float A0 = sA[2*cp], B0 = sB[2*cp];
  float A1 = sA[2*cp+1], B1 = sB[2*cp+1];
  int beg = rp[n], end = rp[n+1];
  float a0 = 0.0f, a1 = 0.0f;
  for (int i=beg; i<end; i++){
    float2 v = unpack_h2(mh[(size_t)i*8 + cp]);
    a0 += lrelu(fmaf(A0, v.x, B0));
    a1 += lrelu(fmaf(A1, v.y, B1));
  }
  float iv = invdeg[n];
  float2* po = (float2*)(xout + (size_t)n*CC + 2*cp);
  *po = make_float2(a0*iv, a1*iv);
}

// ---------- final stage 1: BN stats over 2E rows (both orientations) ----------
__global__ __launch_bounds__(256) void k_final1(const float* __restrict__ x,
    const int* __restrict__ ei, const float* __restrict__ W, const float* __restrict__ b,
    double* __restrict__ st)
{
  __shared__ float sW[512];
  __shared__ float sb16[16];
  __shared__ float sredS[64], sredQ[64];
  for (int i=threadIdx.x; i<512; i+=256) sW[i] = W[i];
  if (threadIdx.x < 16) sb16[threadIdx.x] = b[threadIdx.x];
  __syncthreads();

  int t = blockIdx.x*256 + threadIdx.x;
  bool val = (t < EE);
  float af[16], ab[16];
  if (val){
    int s = ei[t], d = ei[EE+t];
    float4 xs[4], xd[4];
    const float4* p;
    p = (const float4*)(x + (size_t)s*CC); xs[0]=p[0]; xs[1]=p[1]; xs[2]=p[2]; xs[3]=p[3];
    p = (const float4*)(x + (size_t)d*CC); xd[0]=p[0]; xd[1]=p[1]; xd[2]=p[2]; xd[3]=p[3];
#pragma unroll
    for (int c=0;c<CC;c++){
      const float4* wr = (const float4*)(sW + c*32);
      float f = sb16[c], g_ = sb16[c];
#pragma unroll
      for (int q=0;q<4;q++){ float4 w = wr[q];   f = fma4(w, xs[q], f);  g_ = fma4(w, xd[q], g_); }
#pragma unroll
      for (int q=0;q<4;q++){ float4 w = wr[4+q]; f = fma4(w, xd[q], f);  g_ = fma4(w, xs[q], g_); }
      af[c]=f; ab[c]=g_;
    }
  } else {
#pragma unroll
    for (int c=0;c<CC;c++){ af[c]=0.0f; ab[c]=0.0f; }
  }

  int lane = threadIdx.x & 63, w = threadIdx.x >> 6;
#pragma unroll
  for (int c=0;c<CC;c++){
    float rs = af[c] + ab[c];
    float rq = af[c]*af[c] + ab[c]*ab[c];
    rs = waveSum(rs); rq = waveSum(rq);
    if (lane == 0){ sredS[w*16+c] = rs; sredQ[w*16+c] = rq; }
  }
  __syncthreads();
  double* stb = st + (size_t)(blockIdx.x & (NB-1))*32;
  if (threadIdx.x < 16){
    int c = threadIdx.x;
    float tot = sredS[c] + sredS[16+c] + sredS[32+c] + sredS[48+c];
    unsafeAtomicAdd(&stb[c], (double)tot);
  } else if (threadIdx.x < 32){
    int c = threadIdx.x - 16;
    float tot = sredQ[c] + sredQ[16+c] + sredQ[32+c] + sredQ[48+c];
    unsafeAtomicAdd(&stb[16+c], (double)tot);
  }
}

// ---------- final stage 2: recompute, BN+leaky, edge_out + loss ----------
__global__ __launch_bounds__(256) void k_final2(const float* __restrict__ x,
    const int* __restrict__ ei, const float* __restrict__ W, const float* __restrict__ b,
    const double* __restrict__ st, const float* __restrict__ g, const float* __restrict__ bt,
    float* __restrict__ out, double* __restrict__ loss)
{
  __shared__ float sW[512];
  __shared__ float sb16[16];
  __shared__ float sA[16], sB[16];
  __shared__ float sl[4];
  for (int i=threadIdx.x; i<512; i+=256) sW[i] = W[i];
  if (threadIdx.x < 16){
    int c = threadIdx.x;
    sb16[c] = b[c];
    double S = 0.0, Q = 0.0;
#pragma unroll
    for (int k=0;k<NB;k++){ S += st[k*32 + c]; Q += st[k*32 + 16 + c]; }
    double mu  = S * (1.0/(2.0*EE));
    double var = Q * (1.0/(2.0*EE)) - mu*mu;
    float sc = rsqrtf((float)var + 1e-5f);
    float A = sc * g[c];
    sA[c] = A; sB[c] = bt[c] - (float)mu * A;
  }
  __syncthreads();

  int t = blockIdx.x*256 + threadIdx.x;
  bool val = (t < EE);
  float lsum = 0.0f;
  if (val){
    int s = ei[t], d = ei[EE+t];
    float4 xs[4], xd[4];
    const float4* p;
    p = (const float4*)(x + (size_t)s*CC); xs[0]=p[0]; xs[1]=p[1]; xs[2]=p[2]; xs[3]=p[3];
    p = (const float4*)(x + (size_t)d*CC); xd[0]=p[0]; xd[1]=p[1]; xd[2]=p[2]; xd[3]=p[3];
    float fo[16];
#pragma unroll
    for (int c=0;c<CC;c++){
      const float4* wr = (const float4*)(sW + c*32);
      float f = sb16[c], g_ = sb16[c];
#pragma unroll
      for (int q=0;q<4;q++){ float4 w = wr[q];   f = fma4(w, xs[q], f);  g_ = fma4(w, xd[q], g_); }
#pragma unroll
      for (int q=0;q<4;q++){ float4 w = wr[4+q]; f = fma4(w, xd[q], f);  g_ = fma4(w, xs[q], g_); }
      float efv = lrelu(fmaf(sA[c], f,  sB[c]));
      float ebv = lrelu(fmaf(sA[c], g_, sB[c]));
      fo[c] = 0.5f*(efv + ebv);
      float dlt = efv - ebv;
      lsum = fmaf(dlt, dlt, lsum);
    }
    float4* po = (float4*)(out + (size_t)t*CC);
    po[0]=make_float4(fo[0],fo[1],fo[2],fo[3]);
    po[1]=make_float4(fo[4],fo[5],fo[6],fo[7]);
    po[2]=make_float4(fo[8],fo[9],fo[10],fo[11]);
    po[3]=make_float4(fo[12],fo[13],fo[14],fo[15]);
  }
  lsum = waveSum(lsum);
  int lane = threadIdx.x & 63, w = threadIdx.x >> 6;
  if (lane == 0) sl[w] = lsum;
  __syncthreads();
  if (threadIdx.x == 0)
    unsafeAtomicAdd(&loss[blockIdx.x & (NB-1)], (double)(sl[0]+sl[1]+sl[2]+sl[3]));
}

__global__ void k_final3(float* __restrict__ out, const double* __restrict__ loss)
{
  double s = 0.0;
#pragma unroll
  for (int k=0;k<NB;k++) s += loss[k];
  out[(size_t)EE*CC] = (float)(s * (1.0/((double)EE*CC)));
}

// ---------- host ----------
extern "C" void kernel_launch(void* const* d_in, const int* in_sizes, int n_in,
                              void* d_out, int out_size, void* d_ws, size_t ws_size,
                              hipStream_t stream)
{
  (void)in_sizes; (void)n_in; (void)out_size; (void)ws_size;
  const float* ef  = (const float*)d_in[0];
  const int*   ei  = (const int*)d_in[1];
  // d_in[2] = angles (unused by reference forward)
  const float* Wn  = (const float*)d_in[3];
  const float* bn  = (const float*)d_in[4];
  const float* gn  = (const float*)d_in[5];
  const float* btn = (const float*)d_in[6];
  const float* We  = (const float*)d_in[7];
  const float* be  = (const float*)d_in[8];
  const float* ge  = (const float*)d_in[9];
  const float* bte = (const float*)d_in[10];
  float* out = (float*)d_out;
  char* ws = (char*)d_ws;

  size_t off = 0;
  auto alloc = [&](size_t bytes)->size_t{
    size_t r = off; off = (off + bytes + 255) & ~(size_t)255; return r;
  };
  size_t o_xa     = alloc((size_t)NN*CC*4);
  size_t o_xb     = alloc((size_t)NN*CC*4);
  size_t o_mh     = alloc((size_t)EE*8*4);      // fp16 m_hat: E x 16 ch = E x 8 uints
  size_t o_cdst   = alloc((size_t)NN*4);
  size_t o_call   = alloc((size_t)NN*4);
  size_t o_rp     = alloc((size_t)(NN+1)*4);
  size_t o_rpall  = alloc((size_t)(NN+1)*4);
  size_t o_cur    = alloc((size_t)NN*4);
  size_t o_curall = alloc((size_t)NN*4);
  size_t o_sd     = alloc((size_t)EE*8);
  size_t o_listall= alloc((size_t)2*EE*4);
  size_t o_bsum   = alloc(512);
  size_t o_bsum2  = alloc(512);
  size_t o_boff   = alloc(512);
  size_t o_boff2  = alloc(512);
  // stats: 17 layer-slots * NB buckets * 32 doubles, + NB loss doubles
  size_t o_stats  = alloc((size_t)(17*NB*32 + NB)*8);
  size_t o_invdeg = alloc((size_t)NN*4);

  float*  x_a     = (float*)(ws + o_xa);
  float*  x_b     = (float*)(ws + o_xb);
  uint*   m_h     = (uint*)(ws + o_mh);
  int*    cdst    = (int*)(ws + o_cdst);
  int*    call_   = (int*)(ws + o_call);
  int*    rp      = (int*)(ws + o_rp);
  int*    rp_all  = (int*)(ws + o_rpall);
  int*    cur     = (int*)(ws + o_cur);
  int*    cur_all = (int*)(ws + o_curall);
  int2*   sd      = (int2*)(ws + o_sd);
  int*    list_all= (int*)(ws + o_listall);
  int*    bsum    = (int*)(ws + o_bsum);
  int*    bsum2   = (int*)(ws + o_bsum2);
  int*    boff    = (int*)(ws + o_boff);
  int*    boff2   = (int*)(ws + o_boff2);
  double* stats   = (double*)(ws + o_stats);
  double* lossd   = stats + (size_t)17*NB*32;
  float*  invdeg  = (float*)(ws + o_invdeg);

  const int GB_E  = (EE + 255)/256;        // 1563
  const int GB_NC = (NN*CC + 255)/256;     // 6250
  const int GB_NB = NN/NPB;                // 3125 (layer kernels, node-aligned)
  const int NSEG  = (NN + 1023)/1024;      // 98

  hipMemsetAsync(cdst, 0, (size_t)NN*4, stream);
  hipMemsetAsync(call_, 0, (size_t)NN*4, stream);
  hipMemsetAsync(stats, 0, (size_t)(17*NB*32 + NB)*8, stream);

  k_count<<<GB_E, 256, 0, stream>>>(ei, cdst, call_);
  k_scan1<<<NSEG, 256, 0, stream>>>(cdst, rp, bsum, call_, rp_all, bsum2, NN);
  k_scan2<<<1, 256, 0, stream>>>(bsum, boff, bsum2, boff2, NSEG);
  k_scan3<<<NSEG, 256, 0, stream>>>(rp, cur, boff, EE, rp_all, cur_all, boff2, 2*EE, NN);
  k_fill<<<GB_E, 256, 0, stream>>>(ei, cur, sd, cur_all, list_all);
  k_gather0<<<GB_NC, 256, 0, stream>>>(ef, rp_all, list_all, rp, x_a, invdeg);

  const float* xc = x_a;
  float* xn = x_b;
  for (int l = 0; l < LL; ++l){
    double* st = stats + (size_t)l*NB*32;
    const float* Wl = Wn + (size_t)l*CC*2*CC;
    const float* bl = bn + (size_t)l*CC;
    k_edge<<<GB_NB, 256, 0, stream>>>(xc, sd, rp, Wl, bl, m_h, st);
    k_node<<<GB_NB, 256, 0, stream>>>(m_h, rp, invdeg, st,
                                      gn + (size_t)l*CC, btn + (size_t)l*CC, xn);
    float* tmp = (float*)xc; xc = xn; xn = tmp;
  }

  double* stF = stats + (size_t)LL*NB*32;
  k_final1<<<GB_E, 256, 0, stream>>>(xc, ei, We, be, stF);
  k_final2<<<GB_E, 256, 0, stream>>>(xc, ei, We, be, stF, ge, bte, out, lossd);
  k_final3<<<1, 1, 0, stream>>>(out, lossd);
}

// Round 11
// 952.014 us; speedup vs baseline: 2.9284x; 2.9284x over previous
//
#include <hip/hip_runtime.h>
#include <hip/hip_fp16.h>
#include <cstdint>
#include <cstddef>

#define NN 100000
#define EE 400000
#define CC 16
#define LL 16
#define NB 16   // stats atomic buckets

typedef unsigned int uint;

// ---------- device helpers ----------
__device__ __forceinline__ float lrelu(float v){ return v > 0.0f ? v : 0.01f*v; }

__device__ __forceinline__ float waveSum(float v){
#pragma unroll
  for (int off = 32; off >= 1; off >>= 1) v += __shfl_xor(v, off);
  return v;
}

__device__ __forceinline__ float fma4(float4 w, float4 v, float a){
  a = fmaf(w.x, v.x, a); a = fmaf(w.y, v.y, a);
  a = fmaf(w.z, v.z, a); a = fmaf(w.w, v.w, a);
  return a;
}

__device__ __forceinline__ uint pack_h2(float a, float b){
  __half2 h = __floats2half2_rn(a, b);
  return *reinterpret_cast<uint*>(&h);
}
__device__ __forceinline__ float2 unpack_h2(uint v){
  __half2 h = *reinterpret_cast<__half2*>(&v);
  return __half22float2(h);
}

// ---------- init: count dst-degree and src-degree (2 int atomics) ----------
__global__ __launch_bounds__(256) void k_count(const int* __restrict__ ei,
    int* __restrict__ cdst, int* __restrict__ csrc)
{
  int t = blockIdx.x*256 + threadIdx.x;
  if (t >= EE) return;
  int s = ei[t], d = ei[EE + t];
  atomicAdd(&cdst[d], 1);
  atomicAdd(&csrc[s], 1);
}

// ---------- dual exclusive scan (SEG=1024/block) ----------
__device__ __forceinline__ void scan_one(const int* __restrict__ cnt,
    int* __restrict__ rp, int* __restrict__ bsums, int n, int* sd)
{
  int tid = threadIdx.x;
  int base = blockIdx.x*1024 + tid*4;
  int v0=0,v1=0,v2=0,v3=0;
  if (base+0 < n) v0 = cnt[base+0];
  if (base+1 < n) v1 = cnt[base+1];
  if (base+2 < n) v2 = cnt[base+2];
  if (base+3 < n) v3 = cnt[base+3];
  int tot = v0+v1+v2+v3;
  sd[tid] = tot; __syncthreads();
  for (int off=1; off<256; off<<=1){
    int add = (tid>=off) ? sd[tid-off] : 0;
    __syncthreads();
    sd[tid] += add;
    __syncthreads();
  }
  int excl = sd[tid] - tot;
  if (base+0 < n) rp[base+0] = excl;
  if (base+1 < n) rp[base+1] = excl+v0;
  if (base+2 < n) rp[base+2] = excl+v0+v1;
  if (base+3 < n) rp[base+3] = excl+v0+v1+v2;
  if (tid==255) bsums[blockIdx.x] = sd[255];
  __syncthreads();
}

__global__ __launch_bounds__(256) void k_scan1(const int* __restrict__ ca,
    int* __restrict__ rpa, int* __restrict__ bsa,
    const int* __restrict__ cb, int* __restrict__ rpb, int* __restrict__ bsb, int n)
{
  __shared__ int sd[256];
  scan_one(ca, rpa, bsa, n, sd);
  scan_one(cb, rpb, bsb, n, sd);
}

__device__ __forceinline__ void scan2_one(const int* __restrict__ bsums,
    int* __restrict__ boff, int nseg, int* sd)
{
  int tid = threadIdx.x;
  int v = (tid < nseg) ? bsums[tid] : 0;
  sd[tid] = v; __syncthreads();
  for (int off=1; off<256; off<<=1){
    int add = (tid>=off) ? sd[tid-off] : 0;
    __syncthreads();
    sd[tid] += add;
    __syncthreads();
  }
  if (tid < nseg) boff[tid] = sd[tid] - v;
  __syncthreads();
}

__global__ __launch_bounds__(256) void k_scan2(const int* __restrict__ bsa,
    int* __restrict__ boffa, const int* __restrict__ bsb, int* __restrict__ boffb, int nseg)
{
  __shared__ int sd[256];
  scan2_one(bsa, boffa, nseg, sd);
  scan2_one(bsb, boffb, nseg, sd);
}

__global__ __launch_bounds__(256) void k_scan3(
    int* __restrict__ rpa, int* __restrict__ cura, const int* __restrict__ boffa, int totala,
    int* __restrict__ rpb, int* __restrict__ curb, const int* __restrict__ boffb, int totalb, int n)
{
  int adda = boffa[blockIdx.x];
  int addb = boffb[blockIdx.x];
  int base = blockIdx.x*1024 + threadIdx.x*4;
#pragma unroll
  for (int i=0;i<4;i++){
    if (base+i < n){
      int va = rpa[base+i] + adda; rpa[base+i] = va; cura[base+i] = va;
      int vb = rpb[base+i] + addb; rpb[base+i] = vb; curb[base+i] = vb;
    }
  }
  if (blockIdx.x==0 && threadIdx.x==0){ rpa[n] = totala; rpb[n] = totalb; }
}

// ---------- fill: dst-sorted (src,dst,eid) + src-sorted eid list ----------
__global__ __launch_bounds__(256) void k_fill(const int* __restrict__ ei,
    int* __restrict__ cur, int4* __restrict__ sd4,
    int* __restrict__ curs, int* __restrict__ lsrc)
{
  int t = blockIdx.x*256 + threadIdx.x;
  if (t >= EE) return;
  int s = ei[t], d = ei[EE + t];
  int p = atomicAdd(&cur[d], 1);
  sd4[p] = make_int4(s, d, t, 0);
  int ps = atomicAdd(&curs[s], 1);
  lsrc[ps] = t;
}

// ---------- x0 = mean of incident edge features; invdeg = 1/clip(deg_in,1) ----------
__global__ __launch_bounds__(256) void k_gather0(const float* __restrict__ ef,
    const int4* __restrict__ sd4, const int* __restrict__ rp,
    const int* __restrict__ lsrc, const int* __restrict__ rps,
    float* __restrict__ x0, float* __restrict__ invdeg)
{
  int t = blockIdx.x*256 + threadIdx.x;
  if (t >= NN*CC) return;
  int n = t >> 4, c = t & 15;
  int bd = rp[n], ed = rp[n+1];
  int bs = rps[n], es = rps[n+1];
  float acc = 0.0f;
  for (int i=bd; i<ed; i++){
    acc += ef[(size_t)sd4[i].z*CC + c];
  }
  for (int i=bs; i<es; i++){
    acc += ef[(size_t)lsrc[i]*CC + c];
  }
  float dg = fmaxf((float)((ed-bd)+(es-bs)), 1.0f);
  x0[t] = acc / dg;
  if (c == 0){
    invdeg[n] = 1.0f / fmaxf((float)(ed-bd), 1.0f);
  }
}

// ---------- per-layer: m = W @ cat(x[dst],x[src]) + b -> fp16 store + BN stats ----------
// 1 edge per thread
__global__ __launch_bounds__(256) void k_edge(const float* __restrict__ x,
    const int4* __restrict__ sd4,
    const float* __restrict__ W, const float* __restrict__ b,
    uint* __restrict__ mh, double* __restrict__ st)
{
  __shared__ float sW[512];
  __shared__ float sb16[16];
  __shared__ float sredS[64], sredQ[64];
  for (int i=threadIdx.x; i<512; i+=256) sW[i] = W[i];
  if (threadIdx.x < 16) sb16[threadIdx.x] = b[threadIdx.x];
  __syncthreads();

  int t = blockIdx.x*256 + threadIdx.x;
  bool val = (t < EE);
  float acc[16];
  if (val){
    int4 p = sd4[t];
    const float4* xd4 = (const float4*)(x + (size_t)p.y*CC);
    const float4* xs4 = (const float4*)(x + (size_t)p.x*CC);
    float4 xd0=xd4[0], xd1=xd4[1], xd2=xd4[2], xd3=xd4[3];
    float4 xs0=xs4[0], xs1=xs4[1], xs2=xs4[2], xs3=xs4[3];
#pragma unroll
    for (int c=0;c<16;c++){
      const float4* wr = (const float4*)(sW + c*32);
      float a = sb16[c];
      a = fma4(wr[0],xd0,a); a = fma4(wr[1],xd1,a);
      a = fma4(wr[2],xd2,a); a = fma4(wr[3],xd3,a);
      a = fma4(wr[4],xs0,a); a = fma4(wr[5],xs1,a);
      a = fma4(wr[6],xs2,a); a = fma4(wr[7],xs3,a);
      acc[c] = a;
    }
    uint pk[8];
#pragma unroll
    for (int q=0;q<8;q++) pk[q] = pack_h2(acc[2*q], acc[2*q+1]);
    uint4* po = (uint4*)(mh + (size_t)t*8);
    po[0] = make_uint4(pk[0],pk[1],pk[2],pk[3]);
    po[1] = make_uint4(pk[4],pk[5],pk[6],pk[7]);
  } else {
#pragma unroll
    for (int c=0;c<16;c++) acc[c] = 0.0f;
  }

  int lane = threadIdx.x & 63, w = threadIdx.x >> 6;
#pragma unroll
  for (int c=0;c<16;c++){
    float rs = waveSum(acc[c]);
    float rq = waveSum(acc[c]*acc[c]);
    if (lane == 0){ sredS[w*16+c] = rs; sredQ[w*16+c] = rq; }
  }
  __syncthreads();
  double* stb = st + (size_t)(blockIdx.x & (NB-1))*32;
  if (threadIdx.x < 16){
    int c = threadIdx.x;
    float tot = sredS[c] + sredS[16+c] + sredS[32+c] + sredS[48+c];
    unsafeAtomicAdd(&stb[c], (double)tot);
  } else if (threadIdx.x < 32){
    int c = threadIdx.x - 16;
    float tot = sredQ[c] + sredQ[16+c] + sredQ[32+c] + sredQ[48+c];
    unsafeAtomicAdd(&stb[16+c], (double)tot);
  }
}

// ---------- per-layer: finalize BN, leaky, contiguous segment-mean by dst ----------
// 8 threads per node, 2 channels per thread (fp16x2 loads)
__global__ __launch_bounds__(256) void k_node(const uint* __restrict__ mh,
    const int* __restrict__ rp,
    const float* __restrict__ invdeg, const double* __restrict__ st,
    const float* __restrict__ g, const float* __restrict__ bt,
    float* __restrict__ xout)
{
  __shared__ float sA[16], sB[16];
  if (threadIdx.x < 16){
    int c = threadIdx.x;
    double S = 0.0, Q = 0.0;
#pragma unroll
    for (int k=0;k<NB;k++){ S += st[k*32 + c]; Q += st[k*32 + 16 + c]; }
    double mu  = S * (1.0/EE);
    double var = Q * (1.0/EE) - mu*mu;
    float sc = rsqrtf((float)var + 1e-5f);
    float A = sc * g[c];
    sA[c] = A; sB[c] = bt[c] - (float)mu * A;
  }
  __syncthreads();
  int t = blockIdx.x*256 + threadIdx.x;
  int n = t >> 3, cp = t & 7;
  if (n >= NN) return;
  float A0 = sA[2*cp], B0 = sB[2*cp];
  float A1 = sA[2*cp+1], B1 = sB[2*cp+1];
  int beg = rp[n], end = rp[n+1];
  float a0 = 0.0f, a1 = 0.0f;
  for (int i=beg; i<end; i++){
    float2 v = unpack_h2(mh[(size_t)i*8 + cp]);
    a0 += lrelu(fmaf(A0, v.x, B0));
    a1 += lrelu(fmaf(A1, v.y, B1));
  }
  float iv = invdeg[n];
  float2* po = (float2*)(xout + (size_t)n*CC + 2*cp);
  *po = make_float2(a0*iv, a1*iv);
}

// ---------- finals: u,v GEMV (uf = We_L.x + be, vf = We_R.x), fp16 ----------
__global__ __launch_bounds__(256) void k_uvf(const float* __restrict__ x,
    const float* __restrict__ W, const float* __restrict__ b,
    uint* __restrict__ u, uint* __restrict__ v)
{
  __shared__ float sW[512];
  __shared__ float sb16[16];
  for (int i=threadIdx.x; i<512; i+=256) sW[i] = W[i];
  if (threadIdx.x < 16) sb16[threadIdx.x] = b[threadIdx.x];
  __syncthreads();
  int n = blockIdx.x*256 + threadIdx.x;
  if (n >= NN) return;
  const float4* xr = (const float4*)(x + (size_t)n*CC);
  float4 x0 = xr[0], x1 = xr[1], x2 = xr[2], x3 = xr[3];
  uint up[8], vp[8];
#pragma unroll
  for (int q=0;q<8;q++){
    int c0 = 2*q, c1 = 2*q+1;
    const float4* w0 = (const float4*)(sW + c0*32);
    const float4* w1 = (const float4*)(sW + c1*32);
    float u0 = sb16[c0], u1 = sb16[c1], v0 = 0.f, v1 = 0.f;
    u0 = fma4(w0[0],x0,u0); u0 = fma4(w0[1],x1,u0); u0 = fma4(w0[2],x2,u0); u0 = fma4(w0[3],x3,u0);
    v0 = fma4(w0[4],x0,v0); v0 = fma4(w0[5],x1,v0); v0 = fma4(w0[6],x2,v0); v0 = fma4(w0[7],x3,v0);
    u1 = fma4(w1[0],x0,u1); u1 = fma4(w1[1],x1,u1); u1 = fma4(w1[2],x2,u1); u1 = fma4(w1[3],x3,u1);
    v1 = fma4(w1[4],x0,v1); v1 = fma4(w1[5],x1,v1); v1 = fma4(w1[6],x2,v1); v1 = fma4(w1[7],x3,v1);
    up[q] = pack_h2(u0,u1);
    vp[q] = pack_h2(v0,v1);
  }
  uint4* pu = (uint4*)(u + (size_t)n*8);
  pu[0] = make_uint4(up[0],up[1],up[2],up[3]);
  pu[1] = make_uint4(up[4],up[5],up[6],up[7]);
  uint4* pv = (uint4*)(v + (size_t)n*8);
  pv[0] = make_uint4(vp[0],vp[1],vp[2],vp[3]);
  pv[1] = make_uint4(vp[4],vp[5],vp[6],vp[7]);
}

// ---------- final stage 1: BN stats over 2E rows via u/v ----------
__global__ __launch_bounds__(256) void k_final1(
    const uint* __restrict__ uf, const uint* __restrict__ vf,
    const int* __restrict__ ei, double* __restrict__ st)
{
  __shared__ float sredS[64], sredQ[64];
  int t = blockIdx.x*256 + threadIdx.x;
  float ls[16], lq[16];
#pragma unroll
  for (int c=0;c<16;c++){ ls[c]=0.f; lq[c]=0.f; }
  if (t < EE){
    int s = ei[t], d = ei[EE+t];
    const uint4* pus = (const uint4*)(uf + (size_t)s*8);
    const uint4* pvd = (const uint4*)(vf + (size_t)d*8);
    const uint4* pud = (const uint4*)(uf + (size_t)d*8);
    const uint4* pvs = (const uint4*)(vf + (size_t)s*8);
    uint4 us0=pus[0], us1=pus[1], vd0=pvd[0], vd1=pvd[1];
    uint4 ud0=pud[0], ud1=pud[1], vs0=pvs[0], vs1=pvs[1];
    uint usw[8]={us0.x,us0.y,us0.z,us0.w, us1.x,us1.y,us1.z,us1.w};
    uint vdw[8]={vd0.x,vd0.y,vd0.z,vd0.w, vd1.x,vd1.y,vd1.z,vd1.w};
    uint udw[8]={ud0.x,ud0.y,ud0.z,ud0.w, ud1.x,ud1.y,ud1.z,ud1.w};
    uint vsw[8]={vs0.x,vs0.y,vs0.z,vs0.w, vs1.x,vs1.y,vs1.z,vs1.w};
#pragma unroll
    for (int q=0;q<8;q++){
      float2 a = unpack_h2(usw[q]), bq = unpack_h2(vdw[q]);
      float2 cc = unpack_h2(udw[q]), dd = unpack_h2(vsw[q]);
      float f0 = a.x + bq.x, f1 = a.y + bq.y;     // fwd
      float g0 = cc.x + dd.x, g1 = cc.y + dd.y;   // bwd
      ls[2*q]   += f0 + g0; lq[2*q]   += f0*f0 + g0*g0;
      ls[2*q+1] += f1 + g1; lq[2*q+1] += f1*f1 + g1*g1;
    }
  }
  int lane = threadIdx.x & 63, w = threadIdx.x >> 6;
#pragma unroll
  for (int c=0;c<16;c++){
    float rs = waveSum(ls[c]);
    float rq = waveSum(lq[c]);
    if (lane == 0){ sredS[w*16+c] = rs; sredQ[w*16+c] = rq; }
  }
  __syncthreads();
  double* stb = st + (size_t)(blockIdx.x & (NB-1))*32;
  if (threadIdx.x < 16){
    int c = threadIdx.x;
    float tot = sredS[c] + sredS[16+c] + sredS[32+c] + sredS[48+c];
    unsafeAtomicAdd(&stb[c], (double)tot);
  } else if (threadIdx.x < 32){
    int c = threadIdx.x - 16;
    float tot = sredQ[c] + sredQ[16+c] + sredQ[32+c] + sredQ[48+c];
    unsafeAtomicAdd(&stb[16+c], (double)tot);
  }
}

// ---------- final stage 2: BN+leaky via u/v, edge_out + loss ----------
__global__ __launch_bounds__(256) void k_final2(
    const uint* __restrict__ uf, const uint* __restrict__ vf,
    const int* __restrict__ ei, const double* __restrict__ st,
    const float* __restrict__ g, const float* __restrict__ bt,
    float* __restrict__ out, double* __restrict__ loss)
{
  __shared__ float sA[16], sB[16];
  __shared__ float sl[4];
  if (threadIdx.x < 16){
    int c = threadIdx.x;
    double S = 0.0, Q = 0.0;
#pragma unroll
    for (int k=0;k<NB;k++){ S += st[k*32 + c]; Q += st[k*32 + 16 + c]; }
    double mu  = S * (1.0/(2.0*EE));
    double var = Q * (1.0/(2.0*EE)) - mu*mu;
    float sc = rsqrtf((float)var + 1e-5f);
    float A = sc * g[c];
    sA[c] = A; sB[c] = bt[c] - (float)mu * A;
  }
  __syncthreads();

  int t = blockIdx.x*256 + threadIdx.x;
  float lsum = 0.0f;
  if (t < EE){
    int s = ei[t], d = ei[EE+t];
    const uint4* pus = (const uint4*)(uf + (size_t)s*8);
    const uint4* pvd = (const uint4*)(vf + (size_t)d*8);
    const uint4* pud = (const uint4*)(uf + (size_t)d*8);
    const uint4* pvs = (const uint4*)(vf + (size_t)s*8);
    uint4 us0=pus[0], us1=pus[1], vd0=pvd[0], vd1=pvd[1];
    uint4 ud0=pud[0], ud1=pud[1], vs0=pvs[0], vs1=pvs[1];
    uint usw[8]={us0.x,us0.y,us0.z,us0.w, us1.x,us1.y,us1.z,us1.w};
    uint vdw[8]={vd0.x,vd0.y,vd0.z,vd0.w, vd1.x,vd1.y,vd1.z,vd1.w};
    uint udw[8]={ud0.x,ud0.y,ud0.z,ud0.w, ud1.x,ud1.y,ud1.z,ud1.w};
    uint vsw[8]={vs0.x,vs0.y,vs0.z,vs0.w, vs1.x,vs1.y,vs1.z,vs1.w};
    float fo[16];
#pragma unroll
    for (int q=0;q<8;q++){
      float2 a = unpack_h2(usw[q]), bq = unpack_h2(vdw[q]);
      float2 cc = unpack_h2(udw[q]), dd = unpack_h2(vsw[q]);
      int c0 = 2*q, c1 = 2*q+1;
      float e0 = lrelu(fmaf(sA[c0], a.x + bq.x, sB[c0]));
      float b0 = lrelu(fmaf(sA[c0], cc.x + dd.x, sB[c0]));
      float e1 = lrelu(fmaf(sA[c1], a.y + bq.y, sB[c1]));
      float b1 = lrelu(fmaf(sA[c1], cc.y + dd.y, sB[c1]));
      fo[c0] = 0.5f*(e0 + b0);
      fo[c1] = 0.5f*(e1 + b1);
      float d0 = e0 - b0, d1 = e1 - b1;
      lsum = fmaf(d0, d0, lsum);
      lsum = fmaf(d1, d1, lsum);
    }
    float4* po = (float4*)(out + (size_t)t*CC);
    po[0]=make_float4(fo[0],fo[1],fo[2],fo[3]);
    po[1]=make_float4(fo[4],fo[5],fo[6],fo[7]);
    po[2]=make_float4(fo[8],fo[9],fo[10],fo[11]);
    po[3]=make_float4(fo[12],fo[13],fo[14],fo[15]);
  }
  lsum = waveSum(lsum);
  int lane = threadIdx.x & 63, w = threadIdx.x >> 6;
  if (lane == 0) sl[w] = lsum;
  __syncthreads();
  if (threadIdx.x == 0)
    unsafeAtomicAdd(&loss[blockIdx.x & (NB-1)], (double)(sl[0]+sl[1]+sl[2]+sl[3]));
}

__global__ void k_final3(float* __restrict__ out, const double* __restrict__ loss)
{
  double s = 0.0;
#pragma unroll
  for (int k=0;k<NB;k++) s += loss[k];
  out[(size_t)EE*CC] = (float)(s * (1.0/((double)EE*CC)));
}

// ---------- host ----------
extern "C" void kernel_launch(void* const* d_in, const int* in_sizes, int n_in,
                              void* d_out, int out_size, void* d_ws, size_t ws_size,
                              hipStream_t stream)
{
  (void)in_sizes; (void)n_in; (void)out_size; (void)ws_size;
  const float* ef  = (const float*)d_in[0];
  const int*   ei  = (const int*)d_in[1];
  // d_in[2] = angles (unused by reference forward)
  const float* Wn  = (const float*)d_in[3];
  const float* bn  = (const float*)d_in[4];
  const float* gn  = (const float*)d_in[5];
  const float* btn = (const float*)d_in[6];
  const float* We  = (const float*)d_in[7];
  const float* be  = (const float*)d_in[8];
  const float* ge  = (const float*)d_in[9];
  const float* bte = (const float*)d_in[10];
  float* out = (float*)d_out;
  char* ws = (char*)d_ws;

  size_t off = 0;
  auto alloc = [&](size_t bytes)->size_t{
    size_t r = off; off = (off + bytes + 255) & ~(size_t)255; return r;
  };
  size_t o_xa     = alloc((size_t)NN*CC*4);
  size_t o_xb     = alloc((size_t)NN*CC*4);
  size_t o_mh     = alloc((size_t)EE*8*4);      // fp16 m_hat: E x 16 ch = E x 8 uints
  size_t o_uf     = alloc((size_t)NN*8*4);      // fp16 uf
  size_t o_vf     = alloc((size_t)NN*8*4);      // fp16 vf
  size_t o_cdst   = alloc((size_t)NN*4);
  size_t o_csrc   = alloc((size_t)NN*4);
  size_t o_rp     = alloc((size_t)(NN+1)*4);
  size_t o_rps    = alloc((size_t)(NN+1)*4);
  size_t o_cur    = alloc((size_t)NN*4);
  size_t o_curs   = alloc((size_t)NN*4);
  size_t o_sd4    = alloc((size_t)EE*16);
  size_t o_lsrc   = alloc((size_t)EE*4);
  size_t o_bsum   = alloc(512);
  size_t o_bsum2  = alloc(512);
  size_t o_boff   = alloc(512);
  size_t o_boff2  = alloc(512);
  // stats: 17 layer-slots * NB buckets * 32 doubles, + NB loss doubles
  size_t o_stats  = alloc((size_t)(17*NB*32 + NB)*8);
  size_t o_invdeg = alloc((size_t)NN*4);

  float*  x_a     = (float*)(ws + o_xa);
  float*  x_b     = (float*)(ws + o_xb);
  uint*   m_h     = (uint*)(ws + o_mh);
  uint*   u_f     = (uint*)(ws + o_uf);
  uint*   v_f     = (uint*)(ws + o_vf);
  int*    cdst    = (int*)(ws + o_cdst);
  int*    csrc    = (int*)(ws + o_csrc);
  int*    rp      = (int*)(ws + o_rp);
  int*    rps     = (int*)(ws + o_rps);
  int*    cur     = (int*)(ws + o_cur);
  int*    curs    = (int*)(ws + o_curs);
  int4*   sd4     = (int4*)(ws + o_sd4);
  int*    lsrc    = (int*)(ws + o_lsrc);
  int*    bsum    = (int*)(ws + o_bsum);
  int*    bsum2   = (int*)(ws + o_bsum2);
  int*    boff    = (int*)(ws + o_boff);
  int*    boff2   = (int*)(ws + o_boff2);
  double* stats   = (double*)(ws + o_stats);
  double* lossd   = stats + (size_t)17*NB*32;
  float*  invdeg  = (float*)(ws + o_invdeg);

  const int GB_E  = (EE + 255)/256;        // 1563
  const int GB_NC = (NN*CC + 255)/256;     // 6250
  const int GB_N8 = (NN*8 + 255)/256;      // 3125
  const int GB_N  = (NN + 255)/256;        // 391
  const int NSEG  = (NN + 1023)/1024;      // 98

  hipMemsetAsync(cdst, 0, (size_t)NN*4, stream);
  hipMemsetAsync(csrc, 0, (size_t)NN*4, stream);
  hipMemsetAsync(stats, 0, (size_t)(17*NB*32 + NB)*8, stream);

  k_count<<<GB_E, 256, 0, stream>>>(ei, cdst, csrc);
  k_scan1<<<NSEG, 256, 0, stream>>>(cdst, rp, bsum, csrc, rps, bsum2, NN);
  k_scan2<<<1, 256, 0, stream>>>(bsum, boff, bsum2, boff2, NSEG);
  k_scan3<<<NSEG, 256, 0, stream>>>(rp, cur, boff, EE, rps, curs, boff2, EE, NN);
  k_fill<<<GB_E, 256, 0, stream>>>(ei, cur, sd4, curs, lsrc);
  k_gather0<<<GB_NC, 256, 0, stream>>>(ef, sd4, rp, lsrc, rps, x_a, invdeg);

  const float* xc = x_a;
  float* xn = x_b;
  for (int l = 0; l < LL; ++l){
    double* st = stats + (size_t)l*NB*32;
    const float* Wl = Wn + (size_t)l*CC*2*CC;
    const float* bl = bn + (size_t)l*CC;
    k_edge<<<GB_E, 256, 0, stream>>>(xc, sd4, Wl, bl, m_h, st);
    k_node<<<GB_N8, 256, 0, stream>>>(m_h, rp, invdeg, st,
                                      gn + (size_t)l*CC, btn + (size_t)l*CC, xn);
    float* tmp = (float*)xc; xc = xn; xn = tmp;
  }

  double* stF = stats + (size_t)LL*NB*32;
  k_uvf<<<GB_N, 256, 0, stream>>>(xc, We, be, u_f, v_f);
  k_final1<<<GB_E, 256, 0, stream>>>(u_f, v_f, ei, stF);
  k_final2<<<GB_E, 256, 0, stream>>>(u_f, v_f, ei, stF, ge, bte, out, lossd);
  k_final3<<<1, 1, 0, stream>>>(out, lossd);
}

// Round 12
// 775.621 us; speedup vs baseline: 3.5944x; 1.2274x over previous
//
#include <hip/hip_runtime.h>
#include <hip/hip_fp16.h>
#include <cstdint>
#include <cstddef>

#define NN 100000
#define EE 400000
#define CC 16
#define LL 16
#define NB 16   // stats atomic buckets

typedef unsigned int uint;

// ---------- device helpers ----------
__device__ __forceinline__ float lrelu(float v){ return v > 0.0f ? v : 0.01f*v; }

__device__ __forceinline__ float waveSum(float v){
#pragma unroll
  for (int off = 32; off >= 1; off >>= 1) v += __shfl_xor(v, off);
  return v;
}

__device__ __forceinline__ uint pack_h2(float a, float b){
  __half2 h = __floats2half2_rn(a, b);
  return *reinterpret_cast<uint*>(&h);
}
__device__ __forceinline__ float2 unpack_h2(uint v){
  __half2 h = *reinterpret_cast<__half2*>(&v);
  return __half22float2(h);
}

// unpack one fp16 node row (8 uints = 16 ch) into f32[16]
__device__ __forceinline__ void unpack_row(const uint* __restrict__ xh, int n, float* f){
  const uint4* p = (const uint4*)(xh + (size_t)n*8);
  uint4 r0 = p[0], r1 = p[1];
  uint w[8] = {r0.x,r0.y,r0.z,r0.w, r1.x,r1.y,r1.z,r1.w};
#pragma unroll
  for (int q=0;q<8;q++){ float2 v = unpack_h2(w[q]); f[2*q]=v.x; f[2*q+1]=v.y; }
}

// ---------- init: count dst-degree and src-degree (2 int atomics) ----------
__global__ __launch_bounds__(256) void k_count(const int* __restrict__ ei,
    int* __restrict__ cdst, int* __restrict__ csrc)
{
  int t = blockIdx.x*256 + threadIdx.x;
  if (t >= EE) return;
  int s = ei[t], d = ei[EE + t];
  atomicAdd(&cdst[d], 1);
  atomicAdd(&csrc[s], 1);
}

// ---------- dual exclusive scan (SEG=1024/block) ----------
__device__ __forceinline__ void scan_one(const int* __restrict__ cnt,
    int* __restrict__ rp, int* __restrict__ bsums, int n, int* sd)
{
  int tid = threadIdx.x;
  int base = blockIdx.x*1024 + tid*4;
  int v0=0,v1=0,v2=0,v3=0;
  if (base+0 < n) v0 = cnt[base+0];
  if (base+1 < n) v1 = cnt[base+1];
  if (base+2 < n) v2 = cnt[base+2];
  if (base+3 < n) v3 = cnt[base+3];
  int tot = v0+v1+v2+v3;
  sd[tid] = tot; __syncthreads();
  for (int off=1; off<256; off<<=1){
    int add = (tid>=off) ? sd[tid-off] : 0;
    __syncthreads();
    sd[tid] += add;
    __syncthreads();
  }
  int excl = sd[tid] - tot;
  if (base+0 < n) rp[base+0] = excl;
  if (base+1 < n) rp[base+1] = excl+v0;
  if (base+2 < n) rp[base+2] = excl+v0+v1;
  if (base+3 < n) rp[base+3] = excl+v0+v1+v2;
  if (tid==255) bsums[blockIdx.x] = sd[255];
  __syncthreads();
}

__global__ __launch_bounds__(256) void k_scan1(const int* __restrict__ ca,
    int* __restrict__ rpa, int* __restrict__ bsa,
    const int* __restrict__ cb, int* __restrict__ rpb, int* __restrict__ bsb, int n)
{
  __shared__ int sd[256];
  scan_one(ca, rpa, bsa, n, sd);
  scan_one(cb, rpb, bsb, n, sd);
}

__device__ __forceinline__ void scan2_one(const int* __restrict__ bsums,
    int* __restrict__ boff, int nseg, int* sd)
{
  int tid = threadIdx.x;
  int v = (tid < nseg) ? bsums[tid] : 0;
  sd[tid] = v; __syncthreads();
  for (int off=1; off<256; off<<=1){
    int add = (tid>=off) ? sd[tid-off] : 0;
    __syncthreads();
    sd[tid] += add;
    __syncthreads();
  }
  if (tid < nseg) boff[tid] = sd[tid] - v;
  __syncthreads();
}

__global__ __launch_bounds__(256) void k_scan2(const int* __restrict__ bsa,
    int* __restrict__ boffa, const int* __restrict__ bsb, int* __restrict__ boffb, int nseg)
{
  __shared__ int sd[256];
  scan2_one(bsa, boffa, nseg, sd);
  scan2_one(bsb, boffb, nseg, sd);
}

__global__ __launch_bounds__(256) void k_scan3(
    int* __restrict__ rpa, int* __restrict__ cura, const int* __restrict__ boffa, int totala,
    int* __restrict__ rpb, int* __restrict__ curb, const int* __restrict__ boffb, int totalb, int n)
{
  int adda = boffa[blockIdx.x];
  int addb = boffb[blockIdx.x];
  int base = blockIdx.x*1024 + threadIdx.x*4;
#pragma unroll
  for (int i=0;i<4;i++){
    if (base+i < n){
      int va = rpa[base+i] + adda; rpa[base+i] = va; cura[base+i] = va;
      int vb = rpb[base+i] + addb; rpb[base+i] = vb; curb[base+i] = vb;
    }
  }
  if (blockIdx.x==0 && threadIdx.x==0){ rpa[n] = totala; rpb[n] = totalb; }
}

// ---------- fill: dst-sorted (src,dst,eid) + src-sorted eid list ----------
__global__ __launch_bounds__(256) void k_fill(const int* __restrict__ ei,
    int* __restrict__ cur, int4* __restrict__ sd4,
    int* __restrict__ curs, int* __restrict__ lsrc)
{
  int t = blockIdx.x*256 + threadIdx.x;
  if (t >= EE) return;
  int s = ei[t], d = ei[EE + t];
  int p = atomicAdd(&cur[d], 1);
  sd4[p] = make_int4(s, d, t, 0);
  int ps = atomicAdd(&curs[s], 1);
  lsrc[ps] = t;
}

// ---------- x0 (fp16) = mean of incident edge features; invdeg ----------
// 8 threads per node, 2 channels per thread
__global__ __launch_bounds__(256) void k_gather0(const float* __restrict__ ef,
    const int4* __restrict__ sd4, const int* __restrict__ rp,
    const int* __restrict__ lsrc, const int* __restrict__ rps,
    uint* __restrict__ xh, float* __restrict__ invdeg)
{
  int t = blockIdx.x*256 + threadIdx.x;
  if (t >= NN*8) return;
  int n = t >> 3, cp = t & 7;
  int bd = rp[n], ed = rp[n+1];
  int bs = rps[n], es = rps[n+1];
  float a0 = 0.0f, a1 = 0.0f;
  for (int i=bd; i<ed; i++){
    const float2* p = (const float2*)(ef + (size_t)sd4[i].z*CC + 2*cp);
    float2 v = *p;
    a0 += v.x; a1 += v.y;
  }
  for (int i=bs; i<es; i++){
    const float2* p = (const float2*)(ef + (size_t)lsrc[i]*CC + 2*cp);
    float2 v = *p;
    a0 += v.x; a1 += v.y;
  }
  float dg = fmaxf((float)((ed-bd)+(es-bs)), 1.0f);
  xh[(size_t)n*8 + cp] = pack_h2(a0/dg, a1/dg);
  if (cp == 0){
    invdeg[n] = 1.0f / fmaxf((float)(ed-bd), 1.0f);
  }
}

// ---------- per-layer: m = W @ cat(x[dst],x[src]) + b -> fp16 store + BN stats ----------
// 2 edges per thread (MLP), fp16 x rows
__global__ __launch_bounds__(256) void k_edge(const uint* __restrict__ xh,
    const int4* __restrict__ sd4,
    const float* __restrict__ W, const float* __restrict__ b,
    uint* __restrict__ mh, double* __restrict__ st)
{
  __shared__ float sW[512];
  __shared__ float sb16[16];
  __shared__ float sredS[64], sredQ[64];
  for (int i=threadIdx.x; i<512; i+=256) sW[i] = W[i];
  if (threadIdx.x < 16) sb16[threadIdx.x] = b[threadIdx.x];
  __syncthreads();

  int t = blockIdx.x*256 + threadIdx.x;
  int e0 = 2*t, e1 = 2*t+1;
  bool val = (e1 < EE);
  float acc0[16], acc1[16];
  if (val){
    int4 p0 = sd4[e0], p1 = sd4[e1];
    float xa[32], xb[32];
    unpack_row(xh, p0.y, xa);        // dst row
    unpack_row(xh, p0.x, xa + 16);   // src row
    unpack_row(xh, p1.y, xb);
    unpack_row(xh, p1.x, xb + 16);
#pragma unroll
    for (int c=0;c<16;c++){
      const float* wr = sW + c*32;
      float a0 = sb16[c], a1 = sb16[c];
#pragma unroll
      for (int k=0;k<32;k++){
        float w = wr[k];
        a0 = fmaf(w, xa[k], a0);
        a1 = fmaf(w, xb[k], a1);
      }
      acc0[c]=a0; acc1[c]=a1;
    }
    uint w0[8], w1[8];
#pragma unroll
    for (int q=0;q<8;q++){
      w0[q] = pack_h2(acc0[2*q], acc0[2*q+1]);
      w1[q] = pack_h2(acc1[2*q], acc1[2*q+1]);
    }
    uint4* po0 = (uint4*)(mh + (size_t)e0*8);
    po0[0] = make_uint4(w0[0],w0[1],w0[2],w0[3]);
    po0[1] = make_uint4(w0[4],w0[5],w0[6],w0[7]);
    uint4* po1 = (uint4*)(mh + (size_t)e1*8);
    po1[0] = make_uint4(w1[0],w1[1],w1[2],w1[3]);
    po1[1] = make_uint4(w1[4],w1[5],w1[6],w1[7]);
  } else {
#pragma unroll
    for (int c=0;c<16;c++){ acc0[c]=0.0f; acc1[c]=0.0f; }
  }

  int lane = threadIdx.x & 63, w = threadIdx.x >> 6;
#pragma unroll
  for (int c=0;c<16;c++){
    float rs = acc0[c] + acc1[c];
    float rq = acc0[c]*acc0[c] + acc1[c]*acc1[c];
    rs = waveSum(rs); rq = waveSum(rq);
    if (lane == 0){ sredS[w*16+c] = rs; sredQ[w*16+c] = rq; }
  }
  __syncthreads();
  double* stb = st + (size_t)(blockIdx.x & (NB-1))*32;
  if (threadIdx.x < 16){
    int c = threadIdx.x;
    float tot = sredS[c] + sredS[16+c] + sredS[32+c] + sredS[48+c];
    unsafeAtomicAdd(&stb[c], (double)tot);
  } else if (threadIdx.x < 32){
    int c = threadIdx.x - 16;
    float tot = sredQ[c] + sredQ[16+c] + sredQ[32+c] + sredQ[48+c];
    unsafeAtomicAdd(&stb[16+c], (double)tot);
  }
}

// ---------- per-layer: finalize BN, leaky, segment-mean -> fp16 x ----------
// 8 threads per node, 2 channels per thread
__global__ __launch_bounds__(256) void k_node(const uint* __restrict__ mh,
    const int* __restrict__ rp,
    const float* __restrict__ invdeg, const double* __restrict__ st,
    const float* __restrict__ g, const float* __restrict__ bt,
    uint* __restrict__ xhout)
{
  __shared__ float sA[16], sB[16];
  if (threadIdx.x < 16){
    int c = threadIdx.x;
    double S = 0.0, Q = 0.0;
#pragma unroll
    for (int k=0;k<NB;k++){ S += st[k*32 + c]; Q += st[k*32 + 16 + c]; }
    double mu  = S * (1.0/EE);
    double var = Q * (1.0/EE) - mu*mu;
    float sc = rsqrtf((float)var + 1e-5f);
    float A = sc * g[c];
    sA[c] = A; sB[c] = bt[c] - (float)mu * A;
  }
  __syncthreads();
  int t = blockIdx.x*256 + threadIdx.x;
  int n = t >> 3, cp = t & 7;
  if (n >= NN) return;
  float A0 = sA[2*cp], B0 = sB[2*cp];
  float A1 = sA[2*cp+1], B1 = sB[2*cp+1];
  int beg = rp[n], end = rp[n+1];
  float a0 = 0.0f, a1 = 0.0f;
  for (int i=beg; i<end; i++){
    float2 v = unpack_h2(mh[(size_t)i*8 + cp]);
    a0 += lrelu(fmaf(A0, v.x, B0));
    a1 += lrelu(fmaf(A1, v.y, B1));
  }
  float iv = invdeg[n];
  xhout[(size_t)n*8 + cp] = pack_h2(a0*iv, a1*iv);
}

// ---------- finals: u,v GEMV from fp16 x ----------
__global__ __launch_bounds__(256) void k_uvf(const uint* __restrict__ xh,
    const float* __restrict__ W, const float* __restrict__ b,
    uint* __restrict__ u, uint* __restrict__ v)
{
  __shared__ float sW[512];
  __shared__ float sb16[16];
  for (int i=threadIdx.x; i<512; i+=256) sW[i] = W[i];
  if (threadIdx.x < 16) sb16[threadIdx.x] = b[threadIdx.x];
  __syncthreads();
  int n = blockIdx.x*256 + threadIdx.x;
  if (n >= NN) return;
  float xr[16];
  unpack_row(xh, n, xr);
  uint up[8], vp[8];
#pragma unroll
  for (int q=0;q<8;q++){
    int c0 = 2*q, c1 = 2*q+1;
    const float* w0 = sW + c0*32;
    const float* w1 = sW + c1*32;
    float u0 = sb16[c0], u1 = sb16[c1], v0 = 0.f, v1 = 0.f;
#pragma unroll
    for (int k=0;k<16;k++){
      float xv = xr[k];
      u0 = fmaf(w0[k],    xv, u0);
      v0 = fmaf(w0[16+k], xv, v0);
      u1 = fmaf(w1[k],    xv, u1);
      v1 = fmaf(w1[16+k], xv, v1);
    }
    up[q] = pack_h2(u0,u1);
    vp[q] = pack_h2(v0,v1);
  }
  uint4* pu = (uint4*)(u + (size_t)n*8);
  pu[0] = make_uint4(up[0],up[1],up[2],up[3]);
  pu[1] = make_uint4(up[4],up[5],up[6],up[7]);
  uint4* pv = (uint4*)(v + (size_t)n*8);
  pv[0] = make_uint4(vp[0],vp[1],vp[2],vp[3]);
  pv[1] = make_uint4(vp[4],vp[5],vp[6],vp[7]);
}

// ---------- final stage 1: BN stats over 2E rows via u/v ----------
__global__ __launch_bounds__(256) void k_final1(
    const uint* __restrict__ uf, const uint* __restrict__ vf,
    const int* __restrict__ ei, double* __restrict__ st)
{
  __shared__ float sredS[64], sredQ[64];
  int t = blockIdx.x*256 + threadIdx.x;
  float ls[16], lq[16];
#pragma unroll
  for (int c=0;c<16;c++){ ls[c]=0.f; lq[c]=0.f; }
  if (t < EE){
    int s = ei[t], d = ei[EE+t];
    const uint4* pus = (const uint4*)(uf + (size_t)s*8);
    const uint4* pvd = (const uint4*)(vf + (size_t)d*8);
    const uint4* pud = (const uint4*)(uf + (size_t)d*8);
    const uint4* pvs = (const uint4*)(vf + (size_t)s*8);
    uint4 us0=pus[0], us1=pus[1], vd0=pvd[0], vd1=pvd[1];
    uint4 ud0=pud[0], ud1=pud[1], vs0=pvs[0], vs1=pvs[1];
    uint usw[8]={us0.x,us0.y,us0.z,us0.w, us1.x,us1.y,us1.z,us1.w};
    uint vdw[8]={vd0.x,vd0.y,vd0.z,vd0.w, vd1.x,vd1.y,vd1.z,vd1.w};
    uint udw[8]={ud0.x,ud0.y,ud0.z,ud0.w, ud1.x,ud1.y,ud1.z,ud1.w};
    uint vsw[8]={vs0.x,vs0.y,vs0.z,vs0.w, vs1.x,vs1.y,vs1.z,vs1.w};
#pragma unroll
    for (int q=0;q<8;q++){
      float2 a = unpack_h2(usw[q]), bq = unpack_h2(vdw[q]);
      float2 cc = unpack_h2(udw[q]), dd = unpack_h2(vsw[q]);
      float f0 = a.x + bq.x, f1 = a.y + bq.y;     // fwd
      float g0 = cc.x + dd.x, g1 = cc.y + dd.y;   // bwd
      ls[2*q]   += f0 + g0; lq[2*q]   += f0*f0 + g0*g0;
      ls[2*q+1] += f1 + g1; lq[2*q+1] += f1*f1 + g1*g1;
    }
  }
  int lane = threadIdx.x & 63, w = threadIdx.x >> 6;
#pragma unroll
  for (int c=0;c<16;c++){
    float rs = waveSum(ls[c]);
    float rq = waveSum(lq[c]);
    if (lane == 0){ sredS[w*16+c] = rs; sredQ[w*16+c] = rq; }
  }
  __syncthreads();
  double* stb = st + (size_t)(blockIdx.x & (NB-1))*32;
  if (threadIdx.x < 16){
    int c = threadIdx.x;
    float tot = sredS[c] + sredS[16+c] + sredS[32+c] + sredS[48+c];
    unsafeAtomicAdd(&stb[c], (double)tot);
  } else if (threadIdx.x < 32){
    int c = threadIdx.x - 16;
    float tot = sredQ[c] + sredQ[16+c] + sredQ[32+c] + sredQ[48+c];
    unsafeAtomicAdd(&stb[16+c], (double)tot);
  }
}

// ---------- final stage 2: BN+leaky via u/v, edge_out + loss ----------
__global__ __launch_bounds__(256) void k_final2(
    const uint* __restrict__ uf, const uint* __restrict__ vf,
    const int* __restrict__ ei, const double* __restrict__ st,
    const float* __restrict__ g, const float* __restrict__ bt,
    float* __restrict__ out, double* __restrict__ loss)
{
  __shared__ float sA[16], sB[16];
  __shared__ float sl[4];
  if (threadIdx.x < 16){
    int c = threadIdx.x;
    double S = 0.0, Q = 0.0;
#pragma unroll
    for (int k=0;k<NB;k++){ S += st[k*32 + c]; Q += st[k*32 + 16 + c]; }
    double mu  = S * (1.0/(2.0*EE));
    double var = Q * (1.0/(2.0*EE)) - mu*mu;
    float sc = rsqrtf((float)var + 1e-5f);
    float A = sc * g[c];
    sA[c] = A; sB[c] = bt[c] - (float)mu * A;
  }
  __syncthreads();

  int t = blockIdx.x*256 + threadIdx.x;
  float lsum = 0.0f;
  if (t < EE){
    int s = ei[t], d = ei[EE+t];
    const uint4* pus = (const uint4*)(uf + (size_t)s*8);
    const uint4* pvd = (const uint4*)(vf + (size_t)d*8);
    const uint4* pud = (const uint4*)(uf + (size_t)d*8);
    const uint4* pvs = (const uint4*)(vf + (size_t)s*8);
    uint4 us0=pus[0], us1=pus[1], vd0=pvd[0], vd1=pvd[1];
    uint4 ud0=pud[0], ud1=pud[1], vs0=pvs[0], vs1=pvs[1];
    uint usw[8]={us0.x,us0.y,us0.z,us0.w, us1.x,us1.y,us1.z,us1.w};
    uint vdw[8]={vd0.x,vd0.y,vd0.z,vd0.w, vd1.x,vd1.y,vd1.z,vd1.w};
    uint udw[8]={ud0.x,ud0.y,ud0.z,ud0.w, ud1.x,ud1.y,ud1.z,ud1.w};
    uint vsw[8]={vs0.x,vs0.y,vs0.z,vs0.w, vs1.x,vs1.y,vs1.z,vs1.w};
    float fo[16];
#pragma unroll
    for (int q=0;q<8;q++){
      float2 a = unpack_h2(usw[q]), bq = unpack_h2(vdw[q]);
      float2 cc = unpack_h2(udw[q]), dd = unpack_h2(vsw[q]);
      int c0 = 2*q, c1 = 2*q+1;
      float e0 = lrelu(fmaf(sA[c0], a.x + bq.x, sB[c0]));
      float b0 = lrelu(fmaf(sA[c0], cc.x + dd.x, sB[c0]));
      float e1 = lrelu(fmaf(sA[c1], a.y + bq.y, sB[c1]));
      float b1 = lrelu(fmaf(sA[c1], cc.y + dd.y, sB[c1]));
      fo[c0] = 0.5f*(e0 + b0);
      fo[c1] = 0.5f*(e1 + b1);
      float d0 = e0 - b0, d1 = e1 - b1;
      lsum = fmaf(d0, d0, lsum);
      lsum = fmaf(d1, d1, lsum);
    }
    float4* po = (float4*)(out + (size_t)t*CC);
    po[0]=make_float4(fo[0],fo[1],fo[2],fo[3]);
    po[1]=make_float4(fo[4],fo[5],fo[6],fo[7]);
    po[2]=make_float4(fo[8],fo[9],fo[10],fo[11]);
    po[3]=make_float4(fo[12],fo[13],fo[14],fo[15]);
  }
  lsum = waveSum(lsum);
  int lane = threadIdx.x & 63, w = threadIdx.x >> 6;
  if (lane == 0) sl[w] = lsum;
  __syncthreads();
  if (threadIdx.x == 0)
    unsafeAtomicAdd(&loss[blockIdx.x & (NB-1)], (double)(sl[0]+sl[1]+sl[2]+sl[3]));
}

__global__ void k_final3(float* __restrict__ out, const double* __restrict__ loss)
{
  double s = 0.0;
#pragma unroll
  for (int k=0;k<NB;k++) s += loss[k];
  out[(size_t)EE*CC] = (float)(s * (1.0/((double)EE*CC)));
}

// ---------- host ----------
extern "C" void kernel_launch(void* const* d_in, const int* in_sizes, int n_in,
                              void* d_out, int out_size, void* d_ws, size_t ws_size,
                              hipStream_t stream)
{
  (void)in_sizes; (void)n_in; (void)out_size; (void)ws_size;
  const float* ef  = (const float*)d_in[0];
  const int*   ei  = (const int*)d_in[1];
  // d_in[2] = angles (unused by reference forward)
  const float* Wn  = (const float*)d_in[3];
  const float* bn  = (const float*)d_in[4];
  const float* gn  = (const float*)d_in[5];
  const float* btn = (const float*)d_in[6];
  const float* We  = (const float*)d_in[7];
  const float* be  = (const float*)d_in[8];
  const float* ge  = (const float*)d_in[9];
  const float* bte = (const float*)d_in[10];
  float* out = (float*)d_out;
  char* ws = (char*)d_ws;

  size_t off = 0;
  auto alloc = [&](size_t bytes)->size_t{
    size_t r = off; off = (off + bytes + 255) & ~(size_t)255; return r;
  };
  size_t o_xha    = alloc((size_t)NN*8*4);      // fp16 x ping
  size_t o_xhb    = alloc((size_t)NN*8*4);      // fp16 x pong
  size_t o_mh     = alloc((size_t)EE*8*4);      // fp16 m_hat
  size_t o_uf     = alloc((size_t)NN*8*4);      // fp16 uf
  size_t o_vf     = alloc((size_t)NN*8*4);      // fp16 vf
  size_t o_cdst   = alloc((size_t)NN*4);
  size_t o_csrc   = alloc((size_t)NN*4);
  size_t o_rp     = alloc((size_t)(NN+1)*4);
  size_t o_rps    = alloc((size_t)(NN+1)*4);
  size_t o_cur    = alloc((size_t)NN*4);
  size_t o_curs   = alloc((size_t)NN*4);
  size_t o_sd4    = alloc((size_t)EE*16);
  size_t o_lsrc   = alloc((size_t)EE*4);
  size_t o_bsum   = alloc(512);
  size_t o_bsum2  = alloc(512);
  size_t o_boff   = alloc(512);
  size_t o_boff2  = alloc(512);
  size_t o_stats  = alloc((size_t)(17*NB*32 + NB)*8);
  size_t o_invdeg = alloc((size_t)NN*4);

  uint*   xh_a    = (uint*)(ws + o_xha);
  uint*   xh_b    = (uint*)(ws + o_xhb);
  uint*   m_h     = (uint*)(ws + o_mh);
  uint*   u_f     = (uint*)(ws + o_uf);
  uint*   v_f     = (uint*)(ws + o_vf);
  int*    cdst    = (int*)(ws + o_cdst);
  int*    csrc    = (int*)(ws + o_csrc);
  int*    rp      = (int*)(ws + o_rp);
  int*    rps     = (int*)(ws + o_rps);
  int*    cur     = (int*)(ws + o_cur);
  int*    curs    = (int*)(ws + o_curs);
  int4*   sd4     = (int4*)(ws + o_sd4);
  int*    lsrc    = (int*)(ws + o_lsrc);
  int*    bsum    = (int*)(ws + o_bsum);
  int*    bsum2   = (int*)(ws + o_bsum2);
  int*    boff    = (int*)(ws + o_boff);
  int*    boff2   = (int*)(ws + o_boff2);
  double* stats   = (double*)(ws + o_stats);
  double* lossd   = stats + (size_t)17*NB*32;
  float*  invdeg  = (float*)(ws + o_invdeg);

  const int GB_E  = (EE + 255)/256;        // 1563
  const int GB_E2 = (EE/2 + 255)/256;      // 782
  const int GB_N8 = (NN*8 + 255)/256;      // 3125
  const int GB_N  = (NN + 255)/256;        // 391
  const int NSEG  = (NN + 1023)/1024;      // 98

  hipMemsetAsync(cdst, 0, (size_t)NN*4, stream);
  hipMemsetAsync(csrc, 0, (size_t)NN*4, stream);
  hipMemsetAsync(stats, 0, (size_t)(17*NB*32 + NB)*8, stream);

  k_count<<<GB_E, 256, 0, stream>>>(ei, cdst, csrc);
  k_scan1<<<NSEG, 256, 0, stream>>>(cdst, rp, bsum, csrc, rps, bsum2, NN);
  k_scan2<<<1, 256, 0, stream>>>(bsum, boff, bsum2, boff2, NSEG);
  k_scan3<<<NSEG, 256, 0, stream>>>(rp, cur, boff, EE, rps, curs, boff2, EE, NN);
  k_fill<<<GB_E, 256, 0, stream>>>(ei, cur, sd4, curs, lsrc);
  k_gather0<<<GB_N8, 256, 0, stream>>>(ef, sd4, rp, lsrc, rps, xh_a, invdeg);

  uint* xc = xh_a;
  uint* xn = xh_b;
  for (int l = 0; l < LL; ++l){
    double* st = stats + (size_t)l*NB*32;
    const float* Wl = Wn + (size_t)l*CC*2*CC;
    const float* bl = bn + (size_t)l*CC;
    k_edge<<<GB_E2, 256, 0, stream>>>(xc, sd4, Wl, bl, m_h, st);
    k_node<<<GB_N8, 256, 0, stream>>>(m_h, rp, invdeg, st,
                                      gn + (size_t)l*CC, btn + (size_t)l*CC, xn);
    uint* tmp = xc; xc = xn; xn = tmp;
  }

  double* stF = stats + (size_t)LL*NB*32;
  k_uvf<<<GB_N, 256, 0, stream>>>(xc, We, be, u_f, v_f);
  k_final1<<<GB_E, 256, 0, stream>>>(u_f, v_f, ei, stF);
  k_final2<<<GB_E, 256, 0, stream>>>(u_f, v_f, ei, stF, ge, bte, out, lossd);
  k_final3<<<1, 1, 0, stream>>>(out, lossd);
}

// Round 13
// 763.924 us; speedup vs baseline: 3.6494x; 1.0153x over previous
//
#include <hip/hip_runtime.h>
#include <hip/hip_fp16.h>
#include <cstdint>
#include <cstddef>

#define NN 100000
#define EE 400000
#define CC 16
#define LL 16
#define NB 16   // stats atomic buckets

typedef unsigned int uint;

// ---------- device helpers ----------
__device__ __forceinline__ float lrelu(float v){ return v > 0.0f ? v : 0.01f*v; }

__device__ __forceinline__ float waveSum(float v){
#pragma unroll
  for (int off = 32; off >= 1; off >>= 1) v += __shfl_xor(v, off);
  return v;
}

__device__ __forceinline__ uint pack_h2(float a, float b){
  __half2 h = __floats2half2_rn(a, b);
  return *reinterpret_cast<uint*>(&h);
}
__device__ __forceinline__ float2 unpack_h2(uint v){
  __half2 h = *reinterpret_cast<__half2*>(&v);
  return __half22float2(h);
}

// unpack one fp16 node row (8 uints = 16 ch) into f32[16]
__device__ __forceinline__ void unpack_row(const uint* __restrict__ xh, int n, float* f){
  const uint4* p = (const uint4*)(xh + (size_t)n*8);
  uint4 r0 = p[0], r1 = p[1];
  uint w[8] = {r0.x,r0.y,r0.z,r0.w, r1.x,r1.y,r1.z,r1.w};
#pragma unroll
  for (int q=0;q<8;q++){ float2 v = unpack_h2(w[q]); f[2*q]=v.x; f[2*q+1]=v.y; }
}

// ---------- init: count dst-degree and src-degree (2 int atomics) ----------
__global__ __launch_bounds__(256) void k_count(const int* __restrict__ ei,
    int* __restrict__ cdst, int* __restrict__ csrc)
{
  int t = blockIdx.x*256 + threadIdx.x;
  if (t >= EE) return;
  int s = ei[t], d = ei[EE + t];
  atomicAdd(&cdst[d], 1);
  atomicAdd(&csrc[s], 1);
}

// ---------- dual exclusive scan (SEG=1024/block) ----------
__device__ __forceinline__ void scan_one(const int* __restrict__ cnt,
    int* __restrict__ rp, int* __restrict__ bsums, int n, int* sd)
{
  int tid = threadIdx.x;
  int base = blockIdx.x*1024 + tid*4;
  int v0=0,v1=0,v2=0,v3=0;
  if (base+0 < n) v0 = cnt[base+0];
  if (base+1 < n) v1 = cnt[base+1];
  if (base+2 < n) v2 = cnt[base+2];
  if (base+3 < n) v3 = cnt[base+3];
  int tot = v0+v1+v2+v3;
  sd[tid] = tot; __syncthreads();
  for (int off=1; off<256; off<<=1){
    int add = (tid>=off) ? sd[tid-off] : 0;
    __syncthreads();
    sd[tid] += add;
    __syncthreads();
  }
  int excl = sd[tid] - tot;
  if (base+0 < n) rp[base+0] = excl;
  if (base+1 < n) rp[base+1] = excl+v0;
  if (base+2 < n) rp[base+2] = excl+v0+v1;
  if (base+3 < n) rp[base+3] = excl+v0+v1+v2;
  if (tid==255) bsums[blockIdx.x] = sd[255];
  __syncthreads();
}

__global__ __launch_bounds__(256) void k_scan1(const int* __restrict__ ca,
    int* __restrict__ rpa, int* __restrict__ bsa,
    const int* __restrict__ cb, int* __restrict__ rpb, int* __restrict__ bsb, int n)
{
  __shared__ int sd[256];
  scan_one(ca, rpa, bsa, n, sd);
  scan_one(cb, rpb, bsb, n, sd);
}

__device__ __forceinline__ void scan2_one(const int* __restrict__ bsums,
    int* __restrict__ boff, int nseg, int* sd)
{
  int tid = threadIdx.x;
  int v = (tid < nseg) ? bsums[tid] : 0;
  sd[tid] = v; __syncthreads();
  for (int off=1; off<256; off<<=1){
    int add = (tid>=off) ? sd[tid-off] : 0;
    __syncthreads();
    sd[tid] += add;
    __syncthreads();
  }
  if (tid < nseg) boff[tid] = sd[tid] - v;
  __syncthreads();
}

__global__ __launch_bounds__(256) void k_scan2(const int* __restrict__ bsa,
    int* __restrict__ boffa, const int* __restrict__ bsb, int* __restrict__ boffb, int nseg)
{
  __shared__ int sd[256];
  scan2_one(bsa, boffa, nseg, sd);
  scan2_one(bsb, boffb, nseg, sd);
}

__global__ __launch_bounds__(256) void k_scan3(
    int* __restrict__ rpa, int* __restrict__ cura, const int* __restrict__ boffa, int totala,
    int* __restrict__ rpb, int* __restrict__ curb, const int* __restrict__ boffb, int totalb, int n)
{
  int adda = boffa[blockIdx.x];
  int addb = boffb[blockIdx.x];
  int base = blockIdx.x*1024 + threadIdx.x*4;
#pragma unroll
  for (int i=0;i<4;i++){
    if (base+i < n){
      int va = rpa[base+i] + adda; rpa[base+i] = va; cura[base+i] = va;
      int vb = rpb[base+i] + addb; rpb[base+i] = vb; curb[base+i] = vb;
    }
  }
  if (blockIdx.x==0 && threadIdx.x==0){ rpa[n] = totala; rpb[n] = totalb; }
}

// ---------- fill: dst-sorted (src,dst) int2 + eid list, src-sorted eid list ----------
__global__ __launch_bounds__(256) void k_fill(const int* __restrict__ ei,
    int* __restrict__ cur, int2* __restrict__ sdp, int* __restrict__ eidp,
    int* __restrict__ curs, int* __restrict__ lsrc)
{
  int t = blockIdx.x*256 + threadIdx.x;
  if (t >= EE) return;
  int s = ei[t], d = ei[EE + t];
  int p = atomicAdd(&cur[d], 1);
  sdp[p] = make_int2(s, d);
  eidp[p] = t;
  int ps = atomicAdd(&curs[s], 1);
  lsrc[ps] = t;
}

// ---------- x0 (fp16) = mean of incident edge features; invdeg ----------
// 8 threads per node, 2 channels per thread
__global__ __launch_bounds__(256) void k_gather0(const float* __restrict__ ef,
    const int* __restrict__ eidp, const int* __restrict__ rp,
    const int* __restrict__ lsrc, const int* __restrict__ rps,
    uint* __restrict__ xh, float* __restrict__ invdeg)
{
  int t = blockIdx.x*256 + threadIdx.x;
  if (t >= NN*8) return;
  int n = t >> 3, cp = t & 7;
  int bd = rp[n], ed = rp[n+1];
  int bs = rps[n], es = rps[n+1];
  float a0 = 0.0f, a1 = 0.0f;
  for (int i=bd; i<ed; i++){
    const float2* p = (const float2*)(ef + (size_t)eidp[i]*CC + 2*cp);
    float2 v = *p;
    a0 += v.x; a1 += v.y;
  }
  for (int i=bs; i<es; i++){
    const float2* p = (const float2*)(ef + (size_t)lsrc[i]*CC + 2*cp);
    float2 v = *p;
    a0 += v.x; a1 += v.y;
  }
  float dg = fmaxf((float)((ed-bd)+(es-bs)), 1.0f);
  xh[(size_t)n*8 + cp] = pack_h2(a0/dg, a1/dg);
  if (cp == 0){
    invdeg[n] = 1.0f / fmaxf((float)(ed-bd), 1.0f);
  }
}

// ---------- per-layer: m = W @ cat(x[dst],x[src]) + b -> fp16 store + BN stats ----------
// 2 edges per thread, 128-thread blocks (load balance + more blocks in flight)
__global__ __launch_bounds__(128) void k_edge(const uint* __restrict__ xh,
    const int2* __restrict__ sdp,
    const float* __restrict__ W, const float* __restrict__ b,
    uint* __restrict__ mh, double* __restrict__ st)
{
  __shared__ float sW[512];
  __shared__ float sb16[16];
  __shared__ float sredS[32], sredQ[32];
  for (int i=threadIdx.x; i<512; i+=128) sW[i] = W[i];
  if (threadIdx.x < 16) sb16[threadIdx.x] = b[threadIdx.x];
  __syncthreads();

  int t = blockIdx.x*128 + threadIdx.x;
  int e0 = 2*t, e1 = 2*t+1;
  bool val = (e1 < EE);
  float acc0[16], acc1[16];
  if (val){
    int2 p0 = sdp[e0], p1 = sdp[e1];
    float xa[32], xb[32];
    unpack_row(xh, p0.y, xa);        // dst row
    unpack_row(xh, p0.x, xa + 16);   // src row
    unpack_row(xh, p1.y, xb);
    unpack_row(xh, p1.x, xb + 16);
#pragma unroll
    for (int c=0;c<16;c++){
      const float* wr = sW + c*32;
      float a0 = sb16[c], a1 = sb16[c];
#pragma unroll
      for (int k=0;k<32;k++){
        float w = wr[k];
        a0 = fmaf(w, xa[k], a0);
        a1 = fmaf(w, xb[k], a1);
      }
      acc0[c]=a0; acc1[c]=a1;
    }
    uint w0[8], w1[8];
#pragma unroll
    for (int q=0;q<8;q++){
      w0[q] = pack_h2(acc0[2*q], acc0[2*q+1]);
      w1[q] = pack_h2(acc1[2*q], acc1[2*q+1]);
    }
    uint4* po0 = (uint4*)(mh + (size_t)e0*8);
    po0[0] = make_uint4(w0[0],w0[1],w0[2],w0[3]);
    po0[1] = make_uint4(w0[4],w0[5],w0[6],w0[7]);
    uint4* po1 = (uint4*)(mh + (size_t)e1*8);
    po1[0] = make_uint4(w1[0],w1[1],w1[2],w1[3]);
    po1[1] = make_uint4(w1[4],w1[5],w1[6],w1[7]);
  } else {
#pragma unroll
    for (int c=0;c<16;c++){ acc0[c]=0.0f; acc1[c]=0.0f; }
  }

  int lane = threadIdx.x & 63, w = threadIdx.x >> 6;
#pragma unroll
  for (int c=0;c<16;c++){
    float rs = acc0[c] + acc1[c];
    float rq = acc0[c]*acc0[c] + acc1[c]*acc1[c];
    rs = waveSum(rs); rq = waveSum(rq);
    if (lane == 0){ sredS[w*16+c] = rs; sredQ[w*16+c] = rq; }
  }
  __syncthreads();
  double* stb = st + (size_t)(blockIdx.x & (NB-1))*32;
  if (threadIdx.x < 16){
    int c = threadIdx.x;
    float tot = sredS[c] + sredS[16+c];
    unsafeAtomicAdd(&stb[c], (double)tot);
  } else if (threadIdx.x < 32){
    int c = threadIdx.x - 16;
    float tot = sredQ[c] + sredQ[16+c];
    unsafeAtomicAdd(&stb[16+c], (double)tot);
  }
}

// ---------- per-layer: finalize BN, leaky, segment-mean -> fp16 x (or u,v on last) ----------
// 8 threads per node, 2 channels per thread; NN*8 = 3125*256 exact
template<bool LAST>
__global__ __launch_bounds__(256) void k_node(const uint* __restrict__ mh,
    const int* __restrict__ rp,
    const float* __restrict__ invdeg, const double* __restrict__ st,
    const float* __restrict__ g, const float* __restrict__ bt,
    const float* __restrict__ We, const float* __restrict__ be,
    uint* __restrict__ xhout, uint* __restrict__ uf, uint* __restrict__ vf)
{
  __shared__ float sA[16], sB[16];
  __shared__ float sW[512];
  __shared__ float sbn[16];
  __shared__ float sX[32][17];
  const int tid = threadIdx.x;
  if (LAST){
    for (int i=tid;i<512;i+=256) sW[i] = We[i];
    if (tid < 16) sbn[tid] = be[tid];
  }
  if (tid < 16){
    int c = tid;
    double S = 0.0, Q = 0.0;
#pragma unroll
    for (int k=0;k<NB;k++){ S += st[k*32 + c]; Q += st[k*32 + 16 + c]; }
    double mu  = S * (1.0/EE);
    double var = Q * (1.0/EE) - mu*mu;
    float sc = rsqrtf((float)var + 1e-5f);
    float A = sc * g[c];
    sA[c] = A; sB[c] = bt[c] - (float)mu * A;
  }
  __syncthreads();
  int t = blockIdx.x*256 + tid;
  int n = t >> 3, cp = t & 7, nl = tid >> 3;
  float A0 = sA[2*cp], B0 = sB[2*cp];
  float A1 = sA[2*cp+1], B1 = sB[2*cp+1];
  int beg = rp[n], end = rp[n+1];
  float a0 = 0.0f, a1 = 0.0f;
  for (int i=beg; i<end; i++){
    float2 v = unpack_h2(mh[(size_t)i*8 + cp]);
    a0 += lrelu(fmaf(A0, v.x, B0));
    a1 += lrelu(fmaf(A1, v.y, B1));
  }
  float iv = invdeg[n];
  float xv0 = a0*iv, xv1 = a1*iv;

  if (!LAST){
    xhout[(size_t)n*8 + cp] = pack_h2(xv0, xv1);
  } else {
    sX[nl][2*cp] = xv0; sX[nl][2*cp+1] = xv1;
    __syncthreads();
    int c0 = 2*cp, c1 = 2*cp+1;
    const float* w0 = sW + c0*32;
    const float* w1 = sW + c1*32;
    const float* xr = sX[nl];
    float u0 = sbn[c0], u1 = sbn[c1], v0 = 0.f, v1 = 0.f;
#pragma unroll
    for (int k=0;k<16;k++){
      float xv = xr[k];
      u0 = fmaf(w0[k],    xv, u0);
      v0 = fmaf(w0[16+k], xv, v0);
      u1 = fmaf(w1[k],    xv, u1);
      v1 = fmaf(w1[16+k], xv, v1);
    }
    uf[(size_t)n*8 + cp] = pack_h2(u0, u1);
    vf[(size_t)n*8 + cp] = pack_h2(v0, v1);
  }
}

// ---------- final stage 1: BN stats over 2E rows via u/v ----------
__global__ __launch_bounds__(256) void k_final1(
    const uint* __restrict__ uf, const uint* __restrict__ vf,
    const int* __restrict__ ei, double* __restrict__ st)
{
  __shared__ float sredS[64], sredQ[64];
  int t = blockIdx.x*256 + threadIdx.x;
  float ls[16], lq[16];
#pragma unroll
  for (int c=0;c<16;c++){ ls[c]=0.f; lq[c]=0.f; }
  if (t < EE){
    int s = ei[t], d = ei[EE+t];
    const uint4* pus = (const uint4*)(uf + (size_t)s*8);
    const uint4* pvd = (const uint4*)(vf + (size_t)d*8);
    const uint4* pud = (const uint4*)(uf + (size_t)d*8);
    const uint4* pvs = (const uint4*)(vf + (size_t)s*8);
    uint4 us0=pus[0], us1=pus[1], vd0=pvd[0], vd1=pvd[1];
    uint4 ud0=pud[0], ud1=pud[1], vs0=pvs[0], vs1=pvs[1];
    uint usw[8]={us0.x,us0.y,us0.z,us0.w, us1.x,us1.y,us1.z,us1.w};
    uint vdw[8]={vd0.x,vd0.y,vd0.z,vd0.w, vd1.x,vd1.y,vd1.z,vd1.w};
    uint udw[8]={ud0.x,ud0.y,ud0.z,ud0.w, ud1.x,ud1.y,ud1.z,ud1.w};
    uint vsw[8]={vs0.x,vs0.y,vs0.z,vs0.w, vs1.x,vs1.y,vs1.z,vs1.w};
#pragma unroll
    for (int q=0;q<8;q++){
      float2 a = unpack_h2(usw[q]), bq = unpack_h2(vdw[q]);
      float2 cc = unpack_h2(udw[q]), dd = unpack_h2(vsw[q]);
      float f0 = a.x + bq.x, f1 = a.y + bq.y;     // fwd
      float g0 = cc.x + dd.x, g1 = cc.y + dd.y;   // bwd
      ls[2*q]   += f0 + g0; lq[2*q]   += f0*f0 + g0*g0;
      ls[2*q+1] += f1 + g1; lq[2*q+1] += f1*f1 + g1*g1;
    }
  }
  int lane = threadIdx.x & 63, w = threadIdx.x >> 6;
#pragma unroll
  for (int c=0;c<16;c++){
    float rs = waveSum(ls[c]);
    float rq = waveSum(lq[c]);
    if (lane == 0){ sredS[w*16+c] = rs; sredQ[w*16+c] = rq; }
  }
  __syncthreads();
  double* stb = st + (size_t)(blockIdx.x & (NB-1))*32;
  if (threadIdx.x < 16){
    int c = threadIdx.x;
    float tot = sredS[c] + sredS[16+c] + sredS[32+c] + sredS[48+c];
    unsafeAtomicAdd(&stb[c], (double)tot);
  } else if (threadIdx.x < 32){
    int c = threadIdx.x - 16;
    float tot = sredQ[c] + sredQ[16+c] + sredQ[32+c] + sredQ[48+c];
    unsafeAtomicAdd(&stb[16+c], (double)tot);
  }
}

// ---------- final stage 2: BN+leaky via u/v, edge_out + loss ----------
__global__ __launch_bounds__(256) void k_final2(
    const uint* __restrict__ uf, const uint* __restrict__ vf,
    const int* __restrict__ ei, const double* __restrict__ st,
    const float* __restrict__ g, const float* __restrict__ bt,
    float* __restrict__ out, double* __restrict__ loss)
{
  __shared__ float sA[16], sB[16];
  __shared__ float sl[4];
  if (threadIdx.x < 16){
    int c = threadIdx.x;
    double S = 0.0, Q = 0.0;
#pragma unroll
    for (int k=0;k<NB;k++){ S += st[k*32 + c]; Q += st[k*32 + 16 + c]; }
    double mu  = S * (1.0/(2.0*EE));
    double var = Q * (1.0/(2.0*EE)) - mu*mu;
    float sc = rsqrtf((float)var + 1e-5f);
    float A = sc * g[c];
    sA[c] = A; sB[c] = bt[c] - (float)mu * A;
  }
  __syncthreads();

  int t = blockIdx.x*256 + threadIdx.x;
  float lsum = 0.0f;
  if (t < EE){
    int s = ei[t], d = ei[EE+t];
    const uint4* pus = (const uint4*)(uf + (size_t)s*8);
    const uint4* pvd = (const uint4*)(vf + (size_t)d*8);
    const uint4* pud = (const uint4*)(uf + (size_t)d*8);
    const uint4* pvs = (const uint4*)(vf + (size_t)s*8);
    uint4 us0=pus[0], us1=pus[1], vd0=pvd[0], vd1=pvd[1];
    uint4 ud0=pud[0], ud1=pud[1], vs0=pvs[0], vs1=pvs[1];
    uint usw[8]={us0.x,us0.y,us0.z,us0.w, us1.x,us1.y,us1.z,us1.w};
    uint vdw[8]={vd0.x,vd0.y,vd0.z,vd0.w, vd1.x,vd1.y,vd1.z,vd1.w};
    uint udw[8]={ud0.x,ud0.y,ud0.z,ud0.w, ud1.x,ud1.y,ud1.z,ud1.w};
    uint vsw[8]={vs0.x,vs0.y,vs0.z,vs0.w, vs1.x,vs1.y,vs1.z,vs1.w};
    float fo[16];
#pragma unroll
    for (int q=0;q<8;q++){
      float2 a = unpack_h2(usw[q]), bq = unpack_h2(vdw[q]);
      float2 cc = unpack_h2(udw[q]), dd = unpack_h2(vsw[q]);
      int c0 = 2*q, c1 = 2*q+1;
      float e0 = lrelu(fmaf(sA[c0], a.x + bq.x, sB[c0]));
      float b0 = lrelu(fmaf(sA[c0], cc.x + dd.x, sB[c0]));
      float e1 = lrelu(fmaf(sA[c1], a.y + bq.y, sB[c1]));
      float b1 = lrelu(fmaf(sA[c1], cc.y + dd.y, sB[c1]));
      fo[c0] = 0.5f*(e0 + b0);
      fo[c1] = 0.5f*(e1 + b1);
      float d0 = e0 - b0, d1 = e1 - b1;
      lsum = fmaf(d0, d0, lsum);
      lsum = fmaf(d1, d1, lsum);
    }
    float4* po = (float4*)(out + (size_t)t*CC);
    po[0]=make_float4(fo[0],fo[1],fo[2],fo[3]);
    po[1]=make_float4(fo[4],fo[5],fo[6],fo[7]);
    po[2]=make_float4(fo[8],fo[9],fo[10],fo[11]);
    po[3]=make_float4(fo[12],fo[13],fo[14],fo[15]);
  }
  lsum = waveSum(lsum);
  int lane = threadIdx.x & 63, w = threadIdx.x >> 6;
  if (lane == 0) sl[w] = lsum;
  __syncthreads();
  if (threadIdx.x == 0)
    unsafeAtomicAdd(&loss[blockIdx.x & (NB-1)], (double)(sl[0]+sl[1]+sl[2]+sl[3]));
}

__global__ void k_final3(float* __restrict__ out, const double* __restrict__ loss)
{
  double s = 0.0;
#pragma unroll
  for (int k=0;k<NB;k++) s += loss[k];
  out[(size_t)EE*CC] = (float)(s * (1.0/((double)EE*CC)));
}

// ---------- host ----------
extern "C" void kernel_launch(void* const* d_in, const int* in_sizes, int n_in,
                              void* d_out, int out_size, void* d_ws, size_t ws_size,
                              hipStream_t stream)
{
  (void)in_sizes; (void)n_in; (void)out_size; (void)ws_size;
  const float* ef  = (const float*)d_in[0];
  const int*   ei  = (const int*)d_in[1];
  // d_in[2] = angles (unused by reference forward)
  const float* Wn  = (const float*)d_in[3];
  const float* bn  = (const float*)d_in[4];
  const float* gn  = (const float*)d_in[5];
  const float* btn = (const float*)d_in[6];
  const float* We  = (const float*)d_in[7];
  const float* be  = (const float*)d_in[8];
  const float* ge  = (const float*)d_in[9];
  const float* bte = (const float*)d_in[10];
  float* out = (float*)d_out;
  char* ws = (char*)d_ws;

  size_t off = 0;
  auto alloc = [&](size_t bytes)->size_t{
    size_t r = off; off = (off + bytes + 255) & ~(size_t)255; return r;
  };
  const size_t SZN = ((size_t)NN*4 + 255) & ~(size_t)255;  // padded N ints
  size_t o_xha    = alloc((size_t)NN*8*4);      // fp16 x ping
  size_t o_xhb    = alloc((size_t)NN*8*4);      // fp16 x pong
  size_t o_mh     = alloc((size_t)EE*8*4);      // fp16 m_hat
  size_t o_uf     = alloc((size_t)NN*8*4);      // fp16 uf
  size_t o_vf     = alloc((size_t)NN*8*4);      // fp16 vf
  size_t o_cdst   = alloc((size_t)NN*4);        // cdst (csrc must follow)
  size_t o_csrc   = alloc((size_t)NN*4);
  size_t o_rp     = alloc((size_t)(NN+1)*4);
  size_t o_rps    = alloc((size_t)(NN+1)*4);
  size_t o_cur    = alloc((size_t)NN*4);
  size_t o_curs   = alloc((size_t)NN*4);
  size_t o_sdp    = alloc((size_t)EE*8);
  size_t o_eidp   = alloc((size_t)EE*4);
  size_t o_lsrc   = alloc((size_t)EE*4);
  size_t o_bsum   = alloc(512);
  size_t o_bsum2  = alloc(512);
  size_t o_boff   = alloc(512);
  size_t o_boff2  = alloc(512);
  size_t o_stats  = alloc((size_t)(17*NB*32 + NB)*8);
  size_t o_invdeg = alloc((size_t)NN*4);

  uint*   xh_a    = (uint*)(ws + o_xha);
  uint*   xh_b    = (uint*)(ws + o_xhb);
  uint*   m_h     = (uint*)(ws + o_mh);
  uint*   u_f     = (uint*)(ws + o_uf);
  uint*   v_f     = (uint*)(ws + o_vf);
  int*    cdst    = (int*)(ws + o_cdst);
  int*    csrc    = (int*)(ws + o_csrc);
  int*    rp      = (int*)(ws + o_rp);
  int*    rps     = (int*)(ws + o_rps);
  int*    cur     = (int*)(ws + o_cur);
  int*    curs    = (int*)(ws + o_curs);
  int2*   sdp     = (int2*)(ws + o_sdp);
  int*    eidp    = (int*)(ws + o_eidp);
  int*    lsrc    = (int*)(ws + o_lsrc);
  int*    bsum    = (int*)(ws + o_bsum);
  int*    bsum2   = (int*)(ws + o_bsum2);
  int*    boff    = (int*)(ws + o_boff);
  int*    boff2   = (int*)(ws + o_boff2);
  double* stats   = (double*)(ws + o_stats);
  double* lossd   = stats + (size_t)17*NB*32;
  float*  invdeg  = (float*)(ws + o_invdeg);

  const int GB_E  = (EE + 255)/256;        // 1563
  const int GB_E2 = (EE/2 + 127)/128;      // 1563 (128-thread k_edge)
  const int GB_N8 = (NN*8)/256;            // 3125 exact
  const int NSEG  = (NN + 1023)/1024;      // 98

  // cdst and csrc are adjacent: one memset covers both
  hipMemsetAsync(cdst, 0, 2*SZN, stream);
  hipMemsetAsync(stats, 0, (size_t)(17*NB*32 + NB)*8, stream);

  k_count<<<GB_E, 256, 0, stream>>>(ei, cdst, csrc);
  k_scan1<<<NSEG, 256, 0, stream>>>(cdst, rp, bsum, csrc, rps, bsum2, NN);
  k_scan2<<<1, 256, 0, stream>>>(bsum, boff, bsum2, boff2, NSEG);
  k_scan3<<<NSEG, 256, 0, stream>>>(rp, cur, boff, EE, rps, curs, boff2, EE, NN);
  k_fill<<<GB_E, 256, 0, stream>>>(ei, cur, sdp, eidp, curs, lsrc);
  k_gather0<<<GB_N8, 256, 0, stream>>>(ef, eidp, rp, lsrc, rps, xh_a, invdeg);

  uint* xc = xh_a;
  uint* xn = xh_b;
  for (int l = 0; l < LL; ++l){
    double* st = stats + (size_t)l*NB*32;
    const float* Wl = Wn + (size_t)l*CC*2*CC;
    const float* bl = bn + (size_t)l*CC;
    k_edge<<<GB_E2, 128, 0, stream>>>(xc, sdp, Wl, bl, m_h, st);
    if (l < LL-1){
      k_node<false><<<GB_N8, 256, 0, stream>>>(m_h, rp, invdeg, st,
          gn + (size_t)l*CC, btn + (size_t)l*CC, nullptr, nullptr,
          xn, nullptr, nullptr);
      uint* tmp = xc; xc = xn; xn = tmp;
    } else {
      k_node<true><<<GB_N8, 256, 0, stream>>>(m_h, rp, invdeg, st,
          gn + (size_t)l*CC, btn + (size_t)l*CC, We, be,
          nullptr, u_f, v_f);
    }
  }

  double* stF = stats + (size_t)LL*NB*32;
  k_final1<<<GB_E, 256, 0, stream>>>(u_f, v_f, ei, stF);
  k_final2<<<GB_E, 256, 0, stream>>>(u_f, v_f, ei, stF, ge, bte, out, lossd);
  k_final3<<<1, 1, 0, stream>>>(out, lossd);
}